// Round 12
// baseline (306.818 us; speedup 1.0000x reference)
//
#include <hip/hip_runtime.h>

// ======================= MEASUREMENT ROUND =======================
// Identical verified round-11 pipeline, plus 3 duplicate kargmin launches
// writing to scratch (never read). Purpose: K2_warm = (dur_us - 132.5)/3.
// Outputs are bit-identical to round 11.
// =================================================================
// Problem constants: B=1024, D=64, K=512, L=64 (h*w=8*8)
// x (B,D,L); emb/dw (D,K,L); eT (L,K,D); e2T (L,K); countsT (L,K);
// dwT (K,L,D); xT (L,B,D) in WS; idxb (B,L); idxT (L,B)

typedef float f32x4 __attribute__((ext_vector_type(4)));

// ---------------- K1: fused emb transpose + e2 | x transpose | zero counts/loss ----------------
__global__ __launch_bounds__(256) void ktransAll(const float* __restrict__ emb,
                                                 const float* __restrict__ x,
                                                 float* __restrict__ eT,
                                                 float* __restrict__ e2T,
                                                 float* __restrict__ xT,
                                                 float* __restrict__ countsT,
                                                 double* __restrict__ lossAcc) {
  const int t = threadIdx.x;
  __shared__ float s[64][65];
  if (blockIdx.x < 512) {
    const int k = blockIdx.x;
#pragma unroll
    for (int i = 0; i < 16; ++i) {
      int e = t + i * 256;
      int d = e >> 6, l = e & 63;
      s[d][l] = emb[d * 32768 + k * 64 + l];
    }
    __syncthreads();
    if (t < 64) {
      float s2 = 0.f;
#pragma unroll
      for (int d = 0; d < 64; ++d) {
        float v = s[d][t];
        s2 = __fadd_rn(s2, __fmul_rn(v, v));  // round(v*v), sequential-d sum like ref
      }
      e2T[t * 512 + k] = s2;
      countsT[k * 64 + t] = 0.f;   // all 32768 entries zeroed across 512 blocks
    }
    if (k == 0 && t == 0) lossAcc[0] = 0.0;
#pragma unroll
    for (int i = 0; i < 4; ++i) {
      int j = t + i * 256;
      int l = j >> 4, d0 = (j & 15) * 4;
      float4 w;
      w.x = s[d0][l]; w.y = s[d0 + 1][l]; w.z = s[d0 + 2][l]; w.w = s[d0 + 3][l];
      *(float4*)&eT[(l * 512 + k) * 64 + d0] = w;
    }
  } else {
    const int b = blockIdx.x - 512;
    const float* xp = x + b * 4096;
#pragma unroll
    for (int i = 0; i < 4; ++i) {
      int f4 = t + i * 256;
      float4 v = *(const float4*)&xp[f4 * 4];
      int d = f4 >> 4, l0 = (f4 & 15) * 4;
      s[d][l0] = v.x; s[d][l0 + 1] = v.y; s[d][l0 + 2] = v.z; s[d][l0 + 3] = v.w;
    }
    __syncthreads();
#pragma unroll
    for (int i = 0; i < 4; ++i) {
      int j = t + i * 256;
      int l = j >> 4, d0 = (j & 15) * 4;
      float4 w;
      w.x = s[d0][l]; w.y = s[d0 + 1][l]; w.z = s[d0 + 2][l]; w.w = s[d0 + 3][l];
      *(float4*)&xT[((size_t)l * 1024 + b) * 64 + d0] = w;
    }
  }
}

// ---------------- K2: argmin distance GEMM (coalesced xT reads, XCD-local eT) ----------------
// grid (64, 8): x = l, y = b-tile of 128. 256 threads: bg = t&15, kg = t>>4.
__global__ __launch_bounds__(256, 2) void kargmin(const float* __restrict__ xT,
                                                  const float* __restrict__ eT,
                                                  const float* __restrict__ e2T,
                                                  int* __restrict__ idxout,
                                                  int* __restrict__ idxTout,
                                                  float* __restrict__ countsT) {
  const int l = blockIdx.x;                // XCD = l % 8 -> eT slab L2-local
  const int b0 = blockIdx.y * 128;
  const int t = threadIdx.x;
  __shared__ float xs[128][68];
  __shared__ float es[128][68];
  __shared__ float e2s[128];
  const float* xsrc = xT + ((size_t)l * 1024 + b0) * 64;
#pragma unroll
  for (int i = 0; i < 8; ++i) {
    int f4 = t + i * 256;             // 2048 float4 = 128x64, fully coalesced
    int r = f4 >> 4;
    int c = (f4 & 15) * 4;
    *(float4*)&xs[r][c] = *(const float4*)&xsrc[f4 * 4];
  }
  const int bg = t & 15;
  const int kg = t >> 4;
  float bestv[8];
  int bestk[8];
#pragma unroll
  for (int i = 0; i < 8; ++i) { bestv[i] = 3.4e38f; bestk[i] = 0; }

  for (int chunk = 0; chunk < 4; ++chunk) {
    __syncthreads();  // xs ready (iter 0) / prev compute done before es overwrite
    const float* src = eT + (l * 512 + chunk * 128) * 64;
#pragma unroll
    for (int i = 0; i < 8; ++i) {
      int f4 = t + i * 256;            // 2048 float4 = 128x64
      int r = f4 >> 4;
      int c = (f4 & 15) * 4;
      *(float4*)&es[r][c] = *(const float4*)&src[f4 * 4];
    }
    if (t < 128) e2s[t] = e2T[l * 512 + chunk * 128 + t];
    __syncthreads();

    float acc[8][8];
#pragma unroll
    for (int i = 0; i < 8; ++i)
#pragma unroll
      for (int j = 0; j < 8; ++j) acc[i][j] = 0.f;

    for (int d4 = 0; d4 < 16; ++d4) {
      float4 xv[8], ev[8];
#pragma unroll
      for (int i = 0; i < 8; ++i) xv[i] = *(const float4*)&xs[bg + i * 16][d4 * 4];
#pragma unroll
      for (int j = 0; j < 8; ++j) ev[j] = *(const float4*)&es[kg + j * 16][d4 * 4];
#pragma unroll
      for (int i = 0; i < 8; ++i)
#pragma unroll
        for (int j = 0; j < 8; ++j) {
          acc[i][j] = fmaf(xv[i].x, ev[j].x, acc[i][j]);
          acc[i][j] = fmaf(xv[i].y, ev[j].y, acc[i][j]);
          acc[i][j] = fmaf(xv[i].z, ev[j].z, acc[i][j]);
          acc[i][j] = fmaf(xv[i].w, ev[j].w, acc[i][j]);
        }
    }
#pragma unroll
    for (int j = 0; j < 8; ++j) {
      int kk = kg + j * 16;
      int kglob = chunk * 128 + kk;
      float e2v = e2s[kk];
#pragma unroll
      for (int i = 0; i < 8; ++i) {
        float d2 = fmaf(-2.0f, acc[i][j], e2v);  // e2 - 2*xe, single rounding
        if (d2 < bestv[i] || (d2 == bestv[i] && kglob < bestk[i])) {
          bestv[i] = d2; bestk[i] = kglob;
        }
      }
    }
  }
  __syncthreads();
  // cross-kg reduction; reuse es (vals) and xs (k as float, exact for k<512)
  float* rv = &es[0][0];
  float* rkf = &xs[0][0];
#pragma unroll
  for (int i = 0; i < 8; ++i) {
    int bl = bg + i * 16;
    rv[bl * 16 + kg] = bestv[i];
    rkf[bl * 16 + kg] = (float)bestk[i];
  }
  __syncthreads();
  if (t < 128) {
    float bv = rv[t * 16];
    int bk = (int)rkf[t * 16];
#pragma unroll
    for (int g = 1; g < 16; ++g) {
      float v = rv[t * 16 + g];
      int kk = (int)rkf[t * 16 + g];
      if (v < bv || (v == bv && kk < bk)) { bv = v; bk = kk; }
    }
    idxout[(b0 + t) * 64 + l] = bk;
    idxTout[l * 1024 + b0 + t] = bk;
    unsafeAtomicAdd(&countsT[l * 512 + bk], 1.0f);  // integer counts: exact any order
  }
}

// ---------------- K3: role-split — dw-accumulate (256 blocks) + gather (1024 blocks) ----------------
__global__ __launch_bounds__(256) void kdwgather(const float* __restrict__ x,
                                                 const float* __restrict__ xT,
                                                 const float* __restrict__ eT,
                                                 const int* __restrict__ idxb,
                                                 const int* __restrict__ idxT,
                                                 float* __restrict__ dwT,
                                                 float* __restrict__ out_q,
                                                 float* __restrict__ out_enc,
                                                 double* __restrict__ lossAcc) {
  const int t = threadIdx.x;
  __shared__ float SM[8192];   // 32 KB, reused per role
  if (blockIdx.x < 256) {
    const int l = blockIdx.x & 63;
    const int kq = (blockIdx.x >> 6) * 128;
    float* acc = SM;  // 128 k x 64 d
#pragma unroll
    for (int i = 0; i < 32; ++i) acc[t + i * 256] = 0.f;
    const int w = t >> 6, lane = t & 63;
    __syncthreads();
    const int* idxl = idxT + l * 1024;
    const float* xTl = xT + (size_t)l * 65536;
    for (int c = 0; c < 4; ++c) {
      const int base = w * 256 + c * 64;
      const int myidx = idxl[base + lane];
      for (int jj = 0; jj < 64; jj += 8) {
        int ks[8]; float vs[8];
#pragma unroll
        for (int u = 0; u < 8; ++u) ks[u] = __shfl(myidx, jj + u, 64) - kq;  // wave-uniform
#pragma unroll
        for (int u = 0; u < 8; ++u)
          if ((unsigned)ks[u] < 128u)
            vs[u] = xTl[(size_t)(base + jj + u) * 64 + lane];  // coalesced
#pragma unroll
        for (int u = 0; u < 8; ++u)
          if ((unsigned)ks[u] < 128u)
            atomicAdd(&acc[(ks[u] << 6) + lane], vs[u]);  // ds_add_f32
      }
    }
    __syncthreads();
#pragma unroll
    for (int i = 0; i < 32; ++i) {
      int e = t + i * 256;
      int k = e >> 6, d = e & 63;
      dwT[((size_t)(kq + k) * 64 + l) * 64 + d] = acc[e];
    }
  } else {
    const int b = blockIdx.x - 256;
    float (*qb)[68] = (float (*)[68])SM;    // 64x68 = 4352
    int* lidx = (int*)(SM + 4352);          // 64
    double* wsumS = (double*)(SM + 4432);   // 8-aligned
    if (t < 64) lidx[t] = idxb[b * 64 + t];
    __syncthreads();
    const int l = t >> 2, qd = (t & 3) * 16;
    const int kse = lidx[l];
    const float* ep = eT + (l * 512 + kse) * 64 + qd;
#pragma unroll
    for (int j = 0; j < 4; ++j) {
      float4 v = *(const float4*)&ep[j * 4];
      qb[qd + j * 4 + 0][l] = v.x;
      qb[qd + j * 4 + 1][l] = v.y;
      qb[qd + j * 4 + 2][l] = v.z;
      qb[qd + j * 4 + 3][l] = v.w;
    }
    __syncthreads();
    float ls = 0.f;
    const float* xp = x + b * 4096;
    float* op = out_q + b * 4096;
#pragma unroll
    for (int i = 0; i < 4; ++i) {
      int f4 = t + i * 256;
      float4 xv = *(const float4*)&xp[f4 * 4];
      int d = f4 >> 4, l0 = (f4 & 15) * 4;
      float4 qv = *(const float4*)&qb[d][l0];
      f32x4 ov;
      float dx = qv.x - xv.x, dy = qv.y - xv.y, dz = qv.z - xv.z, dw_ = qv.w - xv.w;
      ov.x = xv.x + dx; ov.y = xv.y + dy; ov.z = xv.z + dz; ov.w = xv.w + dw_;
      __builtin_nontemporal_store(ov, (f32x4*)&op[f4 * 4]);  // x + (q - x), streamed
      ls = fmaf(dx, dx, ls); ls = fmaf(dy, dy, ls);
      ls = fmaf(dz, dz, ls); ls = fmaf(dw_, dw_, ls);
    }
    float* encp = out_enc + (size_t)b * 32768;
#pragma unroll
    for (int i = 0; i < 32; ++i) {
      int f4 = t + i * 256;
      int e = f4 * 4;
      int k = e >> 6, l0 = e & 63;
      f32x4 v;
      v.x = (lidx[l0 + 0] == k) ? 1.f : 0.f;
      v.y = (lidx[l0 + 1] == k) ? 1.f : 0.f;
      v.z = (lidx[l0 + 2] == k) ? 1.f : 0.f;
      v.w = (lidx[l0 + 3] == k) ? 1.f : 0.f;
      __builtin_nontemporal_store(v, (f32x4*)&encp[e]);
    }
#pragma unroll
    for (int off = 32; off > 0; off >>= 1) ls += __shfl_down(ls, off, 64);
    if ((t & 63) == 0) wsumS[t >> 6] = (double)ls;
    __syncthreads();
    if (t == 0) unsafeAtomicAdd(lossAcc, wsumS[0] + wsumS[1] + wsumS[2] + wsumS[3]);
  }
}

// ---------------- K4: cs + EMA (k=blk) | perplexity (blk>=512) + loss ----------------
__global__ __launch_bounds__(256) void kemafinal(const float* __restrict__ cluster,
                                                 const float* __restrict__ countsT,
                                                 const float* __restrict__ dw,
                                                 const float* __restrict__ emb,
                                                 const float* __restrict__ dwT,
                                                 const double* __restrict__ lossAcc,
                                                 float* __restrict__ out_cs,
                                                 float* __restrict__ out_emb,
                                                 float* __restrict__ out_dwb,
                                                 float* __restrict__ out_loss,
                                                 float* __restrict__ out_perp) {
  const int t = threadIdx.x;
  if (blockIdx.x >= 512) {
    const int l = blockIdx.x - 512;
    if (t < 64) {
      float s = 0.f;
#pragma unroll
      for (int i = 0; i < 8; ++i) {
        int k = t * 8 + i;
        float p = countsT[l * 512 + k] * (1.0f / 1024.0f);  // exact: /2^10
        s = __fadd_rn(s, __fmul_rn(p, logf(__fadd_rn(p, 1e-10f))));
      }
#pragma unroll
      for (int off = 32; off > 0; off >>= 1) s += __shfl_down(s, off, 64);
      if (t == 0) out_perp[l] = expf(-s) * (1.0f / 512.0f);
    }
    if (blockIdx.x == 512 && t == 64)
      out_loss[0] = (float)(lossAcc[0] / 4194304.0);  // mean over B*D*L
    return;
  }
  const int k = blockIdx.x;
  __shared__ float dwS[64][65];
  __shared__ float csS[64];
  __shared__ float nS;
  const float* sp = dwT + (size_t)k * 4096;
#pragma unroll
  for (int i = 0; i < 4; ++i) {
    int f4 = t + i * 256;
    float4 v = *(const float4*)&sp[f4 * 4];
    int l = f4 >> 4, d0 = (f4 & 15) * 4;
    dwS[l][d0] = v.x; dwS[l][d0 + 1] = v.y; dwS[l][d0 + 2] = v.z; dwS[l][d0 + 3] = v.w;
  }
  const float* cp = cluster + k * 64;
  if (t == 0) {
    float n = 0.f;
#pragma unroll
    for (int l = 0; l < 64; ++l) n = __fadd_rn(n, cp[l]);
    nS = __fadd_rn(n, 1e-06f);
  }
  __syncthreads();
  if (t < 64) {
    const float n = nS;
    const float denom = __fadd_rn(n, 0.000512f);  // n + K*EPS
    float t1 = __fadd_rn(cp[t], 1e-06f);
    float r = __fdiv_rn(t1, denom);
    float r2 = __fmul_rn(r, n);
    float cs = __fadd_rn(__fmul_rn(0.99f, r2), __fmul_rn(0.01f, countsT[t * 512 + k]));
    csS[t] = cs;
    out_cs[k * 64 + t] = cs;
  }
  __syncthreads();
  const int l = t & 63;
  const int dlane = t >> 6;
#pragma unroll
  for (int r = 0; r < 16; ++r) {
    int d = r * 4 + dlane;
    int g = d * 32768 + k * 64 + l;
    float batch = dwS[l][d];
    float buf = 0.99f * dw[g] + 0.01f * (batch / csS[l]);
    out_dwb[g] = buf;
    out_emb[g] = 0.99f * emb[g] + 0.01f * buf;
  }
}

extern "C" void kernel_launch(void* const* d_in, const int* in_sizes, int n_in,
                              void* d_out, int out_size, void* d_ws, size_t ws_size,
                              hipStream_t stream) {
  (void)in_sizes; (void)n_in; (void)out_size; (void)ws_size;
  const float* x    = (const float*)d_in[0];
  const float* emb  = (const float*)d_in[1];
  const float* dw   = (const float*)d_in[2];
  const float* clus = (const float*)d_in[3];

  float* out = (float*)d_out;
  float* out_q    = out;                 // 4194304
  float* out_enc  = out + 4194304;       // 33554432
  float* out_loss = out + 37748736;      // 1
  float* out_perp = out + 37748737;      // 64
  float* out_emb  = out + 37748801;      // 2097152
  float* out_dwb  = out + 39845953;      // 2097152
  float* out_cs   = out + 41943105;      // 32768

  float* wsf = (float*)d_ws;
  float*  dwT     = wsf;                      // 2,097,152 floats (8 MB)
  float*  countsT = wsf + 2097152;            // 32768 (zeroed in K1)
  float*  eT      = wsf + 2129920;            // 2,097,152 (8 MB)
  float*  e2T     = wsf + 4227072;            // 32768
  int*    idxb    = (int*)(wsf + 4259840);    // 65536
  int*    idxT    = (int*)(wsf + 4325376);    // 65536
  double* lossA   = (double*)(wsf + 4390912); // 8 B (zeroed in K1)
  float*  xT      = wsf + 4456448;            // 4,194,304 floats (16 MB)
  // measurement scratch (never read; poison contents irrelevant)
  int*    idx_s   = (int*)(wsf + 8650752);    // 65536
  int*    idxT_s  = (int*)(wsf + 8716288);    // 65536
  float*  cnt_s   = wsf + 8781824;            // 32768  (~35.3 MB total)

  ktransAll<<<1536, 256, 0, stream>>>(emb, x, eT, e2T, xT, countsT, lossA);
  kargmin<<<dim3(64, 8), 256, 0, stream>>>(xT, eT, e2T, idxb, idxT, countsT);
  // --- 3 duplicate K2 launches into scratch: dur_delta = 3 x K2_warm ---
  kargmin<<<dim3(64, 8), 256, 0, stream>>>(xT, eT, e2T, idx_s, idxT_s, cnt_s);
  kargmin<<<dim3(64, 8), 256, 0, stream>>>(xT, eT, e2T, idx_s, idxT_s, cnt_s);
  kargmin<<<dim3(64, 8), 256, 0, stream>>>(xT, eT, e2T, idx_s, idxT_s, cnt_s);
  kdwgather<<<1280, 256, 0, stream>>>(x, xT, eT, idxb, idxT, dwT, out_q, out_enc, lossA);
  kemafinal<<<576, 256, 0, stream>>>(clus, countsT, dw, emb, dwT, lossA,
                                     out_cs, out_emb, out_dwb, out_loss, out_perp);
}

// Round 13
// 171.358 us; speedup vs baseline: 1.7905x; 1.7905x over previous
//
#include <hip/hip_runtime.h>

// Problem constants: B=1024, D=64, K=512, L=64 (h*w=8*8)
// x (B,D,L); emb/dw (D,K,L); eT (L,K,D); e2T (L,K); countsT (L,K);
// dwT (K,L,D); xT (L,B,D) in WS; idxb (B,L); idxT (L,B)
// K2 redesign (r13): x-row per lane in VGPRs, e-rows wave-uniform via scalar
// (SMEM) loads -> pure v_fma(VGPR,SGPR,VGPR) inner loop, no LDS pipe.
// fmaf chain d-ascending per (b,l,k): bit-identical d2 to rounds 7-12.

typedef float f32x4 __attribute__((ext_vector_type(4)));

// ---------------- K1: fused emb transpose + e2 | x transpose | zero counts/loss ----------------
__global__ __launch_bounds__(256) void ktransAll(const float* __restrict__ emb,
                                                 const float* __restrict__ x,
                                                 float* __restrict__ eT,
                                                 float* __restrict__ e2T,
                                                 float* __restrict__ xT,
                                                 float* __restrict__ countsT,
                                                 double* __restrict__ lossAcc) {
  const int t = threadIdx.x;
  __shared__ float s[64][65];
  if (blockIdx.x < 512) {
    const int k = blockIdx.x;
#pragma unroll
    for (int i = 0; i < 16; ++i) {
      int e = t + i * 256;
      int d = e >> 6, l = e & 63;
      s[d][l] = emb[d * 32768 + k * 64 + l];
    }
    __syncthreads();
    if (t < 64) {
      float s2 = 0.f;
#pragma unroll
      for (int d = 0; d < 64; ++d) {
        float v = s[d][t];
        s2 = __fadd_rn(s2, __fmul_rn(v, v));  // round(v*v), sequential-d sum like ref
      }
      e2T[t * 512 + k] = s2;
      countsT[k * 64 + t] = 0.f;   // all 32768 entries zeroed across 512 blocks
    }
    if (k == 0 && t == 0) lossAcc[0] = 0.0;
#pragma unroll
    for (int i = 0; i < 4; ++i) {
      int j = t + i * 256;
      int l = j >> 4, d0 = (j & 15) * 4;
      float4 w;
      w.x = s[d0][l]; w.y = s[d0 + 1][l]; w.z = s[d0 + 2][l]; w.w = s[d0 + 3][l];
      *(float4*)&eT[(l * 512 + k) * 64 + d0] = w;
    }
  } else {
    const int b = blockIdx.x - 512;
    const float* xp = x + b * 4096;
#pragma unroll
    for (int i = 0; i < 4; ++i) {
      int f4 = t + i * 256;
      float4 v = *(const float4*)&xp[f4 * 4];
      int d = f4 >> 4, l0 = (f4 & 15) * 4;
      s[d][l0] = v.x; s[d][l0 + 1] = v.y; s[d][l0 + 2] = v.z; s[d][l0 + 3] = v.w;
    }
    __syncthreads();
#pragma unroll
    for (int i = 0; i < 4; ++i) {
      int j = t + i * 256;
      int l = j >> 4, d0 = (j & 15) * 4;
      float4 w;
      w.x = s[d0][l]; w.y = s[d0 + 1][l]; w.z = s[d0 + 2][l]; w.w = s[d0 + 3][l];
      *(float4*)&xT[((size_t)l * 1024 + b) * 64 + d0] = w;
    }
  }
}

// ---------------- K2: argmin GEMM — x in VGPRs, e via wave-uniform scalar loads ----------------
// grid (64, 16): x = l (XCD = l%8), y = b-tile of 64 (lane = b row).
// 4 waves/block: wave w owns k-quarter [w*128, w*128+128). 16 waves/CU.
__global__ __launch_bounds__(256) void kargmin_s(const float* __restrict__ xT,
                                                 const float* __restrict__ eT,
                                                 const float* __restrict__ e2T,
                                                 int* __restrict__ idxout,
                                                 int* __restrict__ idxTout,
                                                 float* __restrict__ countsT) {
  const int l = blockIdx.x;
  const int b0 = blockIdx.y * 64;
  const int t = threadIdx.x;
  const int lane = t & 63;
  const int w = __builtin_amdgcn_readfirstlane(t >> 6);  // force wave-uniform
  __shared__ float rv[4][64];
  __shared__ float rkf[4][64];

  // each lane: its own x row (b0+lane, l) -> 16 float4 = 64 VGPRs, static indices
  float4 xr[16];
  const float4* xp = (const float4*)(xT + ((size_t)l * 1024 + b0 + lane) * 64);
#pragma unroll
  for (int i = 0; i < 16; ++i) xr[i] = xp[i];

  const float* __restrict__ ew = eT + ((size_t)l * 512 + w * 128) * 64;  // uniform base
  const float* __restrict__ e2w = e2T + l * 512 + w * 128;               // uniform base
  float bestv = 3.4e38f;
  int bestk = 0;

  for (int kk = 0; kk < 128; kk += 2) {      // kk uniform loop counter
    const float* e0 = ew + kk * 64;          // uniform -> scalar loads
    const float* e1 = e0 + 64;
    float a0 = 0.f, a1 = 0.f;
#pragma unroll
    for (int i = 0; i < 16; ++i) {           // d ascending: chain identical to r7-r12
      a0 = fmaf(xr[i].x, e0[i * 4 + 0], a0);
      a0 = fmaf(xr[i].y, e0[i * 4 + 1], a0);
      a0 = fmaf(xr[i].z, e0[i * 4 + 2], a0);
      a0 = fmaf(xr[i].w, e0[i * 4 + 3], a0);
      a1 = fmaf(xr[i].x, e1[i * 4 + 0], a1);
      a1 = fmaf(xr[i].y, e1[i * 4 + 1], a1);
      a1 = fmaf(xr[i].z, e1[i * 4 + 2], a1);
      a1 = fmaf(xr[i].w, e1[i * 4 + 3], a1);
    }
    float d0 = fmaf(-2.0f, a0, e2w[kk]);     // e2 - 2*xe, single rounding
    float d1 = fmaf(-2.0f, a1, e2w[kk + 1]);
    if (d0 < bestv) { bestv = d0; bestk = w * 128 + kk; }      // ascending k:
    if (d1 < bestv) { bestv = d1; bestk = w * 128 + kk + 1; }  // strict < keeps lowest
  }
  rv[w][lane] = bestv;
  rkf[w][lane] = (float)bestk;   // exact for k<512
  __syncthreads();
  if (t < 64) {
    float bv = rv[0][t];
    int bk = (int)rkf[0][t];
#pragma unroll
    for (int g = 1; g < 4; ++g) {
      float v = rv[g][t];
      int kk2 = (int)rkf[g][t];
      if (v < bv || (v == bv && kk2 < bk)) { bv = v; bk = kk2; }
    }
    idxout[(b0 + t) * 64 + l] = bk;
    idxTout[l * 1024 + b0 + t] = bk;
    unsafeAtomicAdd(&countsT[l * 512 + bk], 1.0f);  // integer counts: exact any order
  }
}

// ---------------- K3: role-split — dw-accumulate (256 blocks) + gather (1024 blocks) ----------------
__global__ __launch_bounds__(256) void kdwgather(const float* __restrict__ x,
                                                 const float* __restrict__ xT,
                                                 const float* __restrict__ eT,
                                                 const int* __restrict__ idxb,
                                                 const int* __restrict__ idxT,
                                                 float* __restrict__ dwT,
                                                 float* __restrict__ out_q,
                                                 float* __restrict__ out_enc,
                                                 double* __restrict__ lossAcc) {
  const int t = threadIdx.x;
  __shared__ float SM[8192];   // 32 KB, reused per role
  if (blockIdx.x < 256) {
    const int l = blockIdx.x & 63;
    const int kq = (blockIdx.x >> 6) * 128;
    float* acc = SM;  // 128 k x 64 d
#pragma unroll
    for (int i = 0; i < 32; ++i) acc[t + i * 256] = 0.f;
    const int w = t >> 6, lane = t & 63;
    __syncthreads();
    const int* idxl = idxT + l * 1024;
    const float* xTl = xT + (size_t)l * 65536;
    for (int c = 0; c < 4; ++c) {
      const int base = w * 256 + c * 64;
      const int myidx = idxl[base + lane];
      for (int jj = 0; jj < 64; jj += 8) {
        int ks[8]; float vs[8];
#pragma unroll
        for (int u = 0; u < 8; ++u) ks[u] = __shfl(myidx, jj + u, 64) - kq;  // wave-uniform
#pragma unroll
        for (int u = 0; u < 8; ++u)
          if ((unsigned)ks[u] < 128u)
            vs[u] = xTl[(size_t)(base + jj + u) * 64 + lane];  // coalesced
#pragma unroll
        for (int u = 0; u < 8; ++u)
          if ((unsigned)ks[u] < 128u)
            atomicAdd(&acc[(ks[u] << 6) + lane], vs[u]);  // ds_add_f32
      }
    }
    __syncthreads();
#pragma unroll
    for (int i = 0; i < 32; ++i) {
      int e = t + i * 256;
      int k = e >> 6, d = e & 63;
      dwT[((size_t)(kq + k) * 64 + l) * 64 + d] = acc[e];
    }
  } else {
    const int b = blockIdx.x - 256;
    float (*qb)[68] = (float (*)[68])SM;    // 64x68 = 4352
    int* lidx = (int*)(SM + 4352);          // 64
    double* wsumS = (double*)(SM + 4432);   // 8-aligned
    if (t < 64) lidx[t] = idxb[b * 64 + t];
    __syncthreads();
    const int l = t >> 2, qd = (t & 3) * 16;
    const int kse = lidx[l];
    const float* ep = eT + (l * 512 + kse) * 64 + qd;
#pragma unroll
    for (int j = 0; j < 4; ++j) {
      float4 v = *(const float4*)&ep[j * 4];
      qb[qd + j * 4 + 0][l] = v.x;
      qb[qd + j * 4 + 1][l] = v.y;
      qb[qd + j * 4 + 2][l] = v.z;
      qb[qd + j * 4 + 3][l] = v.w;
    }
    __syncthreads();
    float ls = 0.f;
    const float* xp = x + b * 4096;
    float* op = out_q + b * 4096;
#pragma unroll
    for (int i = 0; i < 4; ++i) {
      int f4 = t + i * 256;
      float4 xv = *(const float4*)&xp[f4 * 4];
      int d = f4 >> 4, l0 = (f4 & 15) * 4;
      float4 qv = *(const float4*)&qb[d][l0];
      f32x4 ov;
      float dx = qv.x - xv.x, dy = qv.y - xv.y, dz = qv.z - xv.z, dw_ = qv.w - xv.w;
      ov.x = xv.x + dx; ov.y = xv.y + dy; ov.z = xv.z + dz; ov.w = xv.w + dw_;
      __builtin_nontemporal_store(ov, (f32x4*)&op[f4 * 4]);  // x + (q - x), streamed
      ls = fmaf(dx, dx, ls); ls = fmaf(dy, dy, ls);
      ls = fmaf(dz, dz, ls); ls = fmaf(dw_, dw_, ls);
    }
    float* encp = out_enc + (size_t)b * 32768;
#pragma unroll
    for (int i = 0; i < 32; ++i) {
      int f4 = t + i * 256;
      int e = f4 * 4;
      int k = e >> 6, l0 = e & 63;
      f32x4 v;
      v.x = (lidx[l0 + 0] == k) ? 1.f : 0.f;
      v.y = (lidx[l0 + 1] == k) ? 1.f : 0.f;
      v.z = (lidx[l0 + 2] == k) ? 1.f : 0.f;
      v.w = (lidx[l0 + 3] == k) ? 1.f : 0.f;
      __builtin_nontemporal_store(v, (f32x4*)&encp[e]);
    }
#pragma unroll
    for (int off = 32; off > 0; off >>= 1) ls += __shfl_down(ls, off, 64);
    if ((t & 63) == 0) wsumS[t >> 6] = (double)ls;
    __syncthreads();
    if (t == 0) unsafeAtomicAdd(lossAcc, wsumS[0] + wsumS[1] + wsumS[2] + wsumS[3]);
  }
}

// ---------------- K4: cs + EMA (k=blk) | perplexity (blk>=512) + loss ----------------
__global__ __launch_bounds__(256) void kemafinal(const float* __restrict__ cluster,
                                                 const float* __restrict__ countsT,
                                                 const float* __restrict__ dw,
                                                 const float* __restrict__ emb,
                                                 const float* __restrict__ dwT,
                                                 const double* __restrict__ lossAcc,
                                                 float* __restrict__ out_cs,
                                                 float* __restrict__ out_emb,
                                                 float* __restrict__ out_dwb,
                                                 float* __restrict__ out_loss,
                                                 float* __restrict__ out_perp) {
  const int t = threadIdx.x;
  if (blockIdx.x >= 512) {
    const int l = blockIdx.x - 512;
    if (t < 64) {
      float s = 0.f;
#pragma unroll
      for (int i = 0; i < 8; ++i) {
        int k = t * 8 + i;
        float p = countsT[l * 512 + k] * (1.0f / 1024.0f);  // exact: /2^10
        s = __fadd_rn(s, __fmul_rn(p, logf(__fadd_rn(p, 1e-10f))));
      }
#pragma unroll
      for (int off = 32; off > 0; off >>= 1) s += __shfl_down(s, off, 64);
      if (t == 0) out_perp[l] = expf(-s) * (1.0f / 512.0f);
    }
    if (blockIdx.x == 512 && t == 64)
      out_loss[0] = (float)(lossAcc[0] / 4194304.0);  // mean over B*D*L
    return;
  }
  const int k = blockIdx.x;
  __shared__ float dwS[64][65];
  __shared__ float csS[64];
  __shared__ float nS;
  const float* sp = dwT + (size_t)k * 4096;
#pragma unroll
  for (int i = 0; i < 4; ++i) {
    int f4 = t + i * 256;
    float4 v = *(const float4*)&sp[f4 * 4];
    int l = f4 >> 4, d0 = (f4 & 15) * 4;
    dwS[l][d0] = v.x; dwS[l][d0 + 1] = v.y; dwS[l][d0 + 2] = v.z; dwS[l][d0 + 3] = v.w;
  }
  const float* cp = cluster + k * 64;
  if (t == 0) {
    float n = 0.f;
#pragma unroll
    for (int l = 0; l < 64; ++l) n = __fadd_rn(n, cp[l]);
    nS = __fadd_rn(n, 1e-06f);
  }
  __syncthreads();
  if (t < 64) {
    const float n = nS;
    const float denom = __fadd_rn(n, 0.000512f);  // n + K*EPS
    float t1 = __fadd_rn(cp[t], 1e-06f);
    float r = __fdiv_rn(t1, denom);
    float r2 = __fmul_rn(r, n);
    float cs = __fadd_rn(__fmul_rn(0.99f, r2), __fmul_rn(0.01f, countsT[t * 512 + k]));
    csS[t] = cs;
    out_cs[k * 64 + t] = cs;
  }
  __syncthreads();
  const int l = t & 63;
  const int dlane = t >> 6;
#pragma unroll
  for (int r = 0; r < 16; ++r) {
    int d = r * 4 + dlane;
    int g = d * 32768 + k * 64 + l;
    float batch = dwS[l][d];
    float buf = 0.99f * dw[g] + 0.01f * (batch / csS[l]);
    out_dwb[g] = buf;
    out_emb[g] = 0.99f * emb[g] + 0.01f * buf;
  }
}

extern "C" void kernel_launch(void* const* d_in, const int* in_sizes, int n_in,
                              void* d_out, int out_size, void* d_ws, size_t ws_size,
                              hipStream_t stream) {
  (void)in_sizes; (void)n_in; (void)out_size; (void)ws_size;
  const float* x    = (const float*)d_in[0];
  const float* emb  = (const float*)d_in[1];
  const float* dw   = (const float*)d_in[2];
  const float* clus = (const float*)d_in[3];

  float* out = (float*)d_out;
  float* out_q    = out;                 // 4194304
  float* out_enc  = out + 4194304;       // 33554432
  float* out_loss = out + 37748736;      // 1
  float* out_perp = out + 37748737;      // 64
  float* out_emb  = out + 37748801;      // 2097152
  float* out_dwb  = out + 39845953;      // 2097152
  float* out_cs   = out + 41943105;      // 32768

  float* wsf = (float*)d_ws;
  float*  dwT     = wsf;                      // 2,097,152 floats (8 MB)
  float*  countsT = wsf + 2097152;            // 32768 (zeroed in K1)
  float*  eT      = wsf + 2129920;            // 2,097,152 (8 MB)
  float*  e2T     = wsf + 4227072;            // 32768
  int*    idxb    = (int*)(wsf + 4259840);    // 65536
  int*    idxT    = (int*)(wsf + 4325376);    // 65536
  double* lossA   = (double*)(wsf + 4390912); // 8 B (zeroed in K1)
  float*  xT      = wsf + 4456448;            // 4,194,304 floats (16 MB)

  ktransAll<<<1536, 256, 0, stream>>>(emb, x, eT, e2T, xT, countsT, lossA);
  kargmin_s<<<dim3(64, 16), 256, 0, stream>>>(xT, eT, e2T, idxb, idxT, countsT);
  kdwgather<<<1280, 256, 0, stream>>>(x, xT, eT, idxb, idxT, dwT, out_q, out_enc, lossA);
  kemafinal<<<576, 256, 0, stream>>>(clus, countsT, dw, emb, dwT, lossA,
                                     out_cs, out_emb, out_dwb, out_loss, out_perp);
}

// Round 14
// 165.080 us; speedup vs baseline: 1.8586x; 1.0380x over previous
//
#include <hip/hip_runtime.h>

// Problem constants: B=1024, D=64, K=512, L=64 (h*w=8*8)
// x (B,D,L); emb/dw (D,K,L); eT (L,K,D); e2T (L,K); countsT (L,K);
// dwT (K,L,D); xT (L,B,D) in WS; idxb (B,L); idxT (L,B)
// K2 (r14): r13 design + asm-pinned x registers (r13 failed because the
// compiler rematerialized the x loads inside the k-loop: VGPR=36, FETCH=16.5GB).
// Inner loop target: v_fma(VGPR, SGPR, VGPR), e-rows via wave-uniform s_load.
// fmaf chain d-ascending per (b,l,k): bit-identical d2 to rounds 7-13.

typedef float f32x4 __attribute__((ext_vector_type(4)));

// ---------------- K1: fused emb transpose + e2 | x transpose | zero counts/loss ----------------
__global__ __launch_bounds__(256) void ktransAll(const float* __restrict__ emb,
                                                 const float* __restrict__ x,
                                                 float* __restrict__ eT,
                                                 float* __restrict__ e2T,
                                                 float* __restrict__ xT,
                                                 float* __restrict__ countsT,
                                                 double* __restrict__ lossAcc) {
  const int t = threadIdx.x;
  __shared__ float s[64][65];
  if (blockIdx.x < 512) {
    const int k = blockIdx.x;
#pragma unroll
    for (int i = 0; i < 16; ++i) {
      int e = t + i * 256;
      int d = e >> 6, l = e & 63;
      s[d][l] = emb[d * 32768 + k * 64 + l];
    }
    __syncthreads();
    if (t < 64) {
      float s2 = 0.f;
#pragma unroll
      for (int d = 0; d < 64; ++d) {
        float v = s[d][t];
        s2 = __fadd_rn(s2, __fmul_rn(v, v));  // round(v*v), sequential-d sum like ref
      }
      e2T[t * 512 + k] = s2;
      countsT[k * 64 + t] = 0.f;   // all 32768 entries zeroed across 512 blocks
    }
    if (k == 0 && t == 0) lossAcc[0] = 0.0;
#pragma unroll
    for (int i = 0; i < 4; ++i) {
      int j = t + i * 256;
      int l = j >> 4, d0 = (j & 15) * 4;
      float4 w;
      w.x = s[d0][l]; w.y = s[d0 + 1][l]; w.z = s[d0 + 2][l]; w.w = s[d0 + 3][l];
      *(float4*)&eT[(l * 512 + k) * 64 + d0] = w;
    }
  } else {
    const int b = blockIdx.x - 512;
    const float* xp = x + b * 4096;
#pragma unroll
    for (int i = 0; i < 4; ++i) {
      int f4 = t + i * 256;
      float4 v = *(const float4*)&xp[f4 * 4];
      int d = f4 >> 4, l0 = (f4 & 15) * 4;
      s[d][l0] = v.x; s[d][l0 + 1] = v.y; s[d][l0 + 2] = v.z; s[d][l0 + 3] = v.w;
    }
    __syncthreads();
#pragma unroll
    for (int i = 0; i < 4; ++i) {
      int j = t + i * 256;
      int l = j >> 4, d0 = (j & 15) * 4;
      float4 w;
      w.x = s[d0][l]; w.y = s[d0 + 1][l]; w.z = s[d0 + 2][l]; w.w = s[d0 + 3][l];
      *(float4*)&xT[((size_t)l * 1024 + b) * 64 + d0] = w;
    }
  }
}

// ---------------- K2: argmin GEMM — x pinned in VGPRs, e via wave-uniform scalar loads ----------------
// grid (64, 16): x = l (XCD = l%8), y = b-tile of 64 (lane = b row).
// 4 waves/block: wave w owns k-quarter [w*128, w*128+128).
__global__ __launch_bounds__(256) void kargmin_s2(const float* __restrict__ xT,
                                                  const float* __restrict__ eT,
                                                  const float* __restrict__ e2T,
                                                  int* __restrict__ idxout,
                                                  int* __restrict__ idxTout,
                                                  float* __restrict__ countsT) {
  const int l = blockIdx.x;
  const int b0 = blockIdx.y * 64;
  const int t = threadIdx.x;
  const int lane = t & 63;
  const int w = __builtin_amdgcn_readfirstlane(t >> 6);  // force wave-uniform
  __shared__ float rv[4][64];
  __shared__ float rkf[4][64];

  // each lane: its own x row (b0+lane, l) -> 16 float4 = 64 VGPRs.
  // asm pin: value becomes opaque -> compiler cannot rematerialize the load
  // inside the k-loop (r13 failure mode: VGPR=36, FETCH_SIZE=16.5GB).
  f32x4 xr[16];
  const f32x4* xp = (const f32x4*)(xT + ((size_t)l * 1024 + b0 + lane) * 64);
#pragma unroll
  for (int i = 0; i < 16; ++i) {
    xr[i] = xp[i];
    asm volatile("" : "+v"(xr[i]));   // pin in VGPRs
  }

  const float* __restrict__ ew = eT + ((size_t)l * 512 + w * 128) * 64;  // uniform base
  const float* __restrict__ e2w = e2T + l * 512 + w * 128;               // uniform base
  float bestv = 3.4e38f;
  int bestk = 0;

#pragma unroll 2
  for (int kk = 0; kk < 128; kk += 2) {      // kk uniform loop counter
    const float* e0 = ew + kk * 64;          // uniform -> scalar loads
    const float* e1 = e0 + 64;
    float a0 = 0.f, a1 = 0.f;
#pragma unroll
    for (int i = 0; i < 16; ++i) {           // d ascending: chain identical to r7-r13
      a0 = fmaf(xr[i].x, e0[i * 4 + 0], a0);
      a0 = fmaf(xr[i].y, e0[i * 4 + 1], a0);
      a0 = fmaf(xr[i].z, e0[i * 4 + 2], a0);
      a0 = fmaf(xr[i].w, e0[i * 4 + 3], a0);
      a1 = fmaf(xr[i].x, e1[i * 4 + 0], a1);
      a1 = fmaf(xr[i].y, e1[i * 4 + 1], a1);
      a1 = fmaf(xr[i].z, e1[i * 4 + 2], a1);
      a1 = fmaf(xr[i].w, e1[i * 4 + 3], a1);
    }
    float d0 = fmaf(-2.0f, a0, e2w[kk]);     // e2 - 2*xe, single rounding
    float d1 = fmaf(-2.0f, a1, e2w[kk + 1]);
    if (d0 < bestv) { bestv = d0; bestk = w * 128 + kk; }      // ascending k:
    if (d1 < bestv) { bestv = d1; bestk = w * 128 + kk + 1; }  // strict < keeps lowest
  }
  rv[w][lane] = bestv;
  rkf[w][lane] = (float)bestk;   // exact for k<512
  __syncthreads();
  if (t < 64) {
    float bv = rv[0][t];
    int bk = (int)rkf[0][t];
#pragma unroll
    for (int g = 1; g < 4; ++g) {
      float v = rv[g][t];
      int kk2 = (int)rkf[g][t];
      if (v < bv || (v == bv && kk2 < bk)) { bv = v; bk = kk2; }
    }
    idxout[(b0 + t) * 64 + l] = bk;
    idxTout[l * 1024 + b0 + t] = bk;
    unsafeAtomicAdd(&countsT[l * 512 + bk], 1.0f);  // integer counts: exact any order
  }
}

// ---------------- K3: role-split — dw-accumulate (256 blocks) + gather (1024 blocks) ----------------
__global__ __launch_bounds__(256) void kdwgather(const float* __restrict__ x,
                                                 const float* __restrict__ xT,
                                                 const float* __restrict__ eT,
                                                 const int* __restrict__ idxb,
                                                 const int* __restrict__ idxT,
                                                 float* __restrict__ dwT,
                                                 float* __restrict__ out_q,
                                                 float* __restrict__ out_enc,
                                                 double* __restrict__ lossAcc) {
  const int t = threadIdx.x;
  __shared__ float SM[8192];   // 32 KB, reused per role
  if (blockIdx.x < 256) {
    const int l = blockIdx.x & 63;
    const int kq = (blockIdx.x >> 6) * 128;
    float* acc = SM;  // 128 k x 64 d
#pragma unroll
    for (int i = 0; i < 32; ++i) acc[t + i * 256] = 0.f;
    const int w = t >> 6, lane = t & 63;
    __syncthreads();
    const int* idxl = idxT + l * 1024;
    const float* xTl = xT + (size_t)l * 65536;
    for (int c = 0; c < 4; ++c) {
      const int base = w * 256 + c * 64;
      const int myidx = idxl[base + lane];
      for (int jj = 0; jj < 64; jj += 8) {
        int ks[8]; float vs[8];
#pragma unroll
        for (int u = 0; u < 8; ++u) ks[u] = __shfl(myidx, jj + u, 64) - kq;  // wave-uniform
#pragma unroll
        for (int u = 0; u < 8; ++u)
          if ((unsigned)ks[u] < 128u)
            vs[u] = xTl[(size_t)(base + jj + u) * 64 + lane];  // coalesced
#pragma unroll
        for (int u = 0; u < 8; ++u)
          if ((unsigned)ks[u] < 128u)
            atomicAdd(&acc[(ks[u] << 6) + lane], vs[u]);  // ds_add_f32
      }
    }
    __syncthreads();
#pragma unroll
    for (int i = 0; i < 32; ++i) {
      int e = t + i * 256;
      int k = e >> 6, d = e & 63;
      dwT[((size_t)(kq + k) * 64 + l) * 64 + d] = acc[e];
    }
  } else {
    const int b = blockIdx.x - 256;
    float (*qb)[68] = (float (*)[68])SM;    // 64x68 = 4352
    int* lidx = (int*)(SM + 4352);          // 64
    double* wsumS = (double*)(SM + 4432);   // 8-aligned
    if (t < 64) lidx[t] = idxb[b * 64 + t];
    __syncthreads();
    const int l = t >> 2, qd = (t & 3) * 16;
    const int kse = lidx[l];
    const float* ep = eT + (l * 512 + kse) * 64 + qd;
#pragma unroll
    for (int j = 0; j < 4; ++j) {
      float4 v = *(const float4*)&ep[j * 4];
      qb[qd + j * 4 + 0][l] = v.x;
      qb[qd + j * 4 + 1][l] = v.y;
      qb[qd + j * 4 + 2][l] = v.z;
      qb[qd + j * 4 + 3][l] = v.w;
    }
    __syncthreads();
    float ls = 0.f;
    const float* xp = x + b * 4096;
    float* op = out_q + b * 4096;
#pragma unroll
    for (int i = 0; i < 4; ++i) {
      int f4 = t + i * 256;
      float4 xv = *(const float4*)&xp[f4 * 4];
      int d = f4 >> 4, l0 = (f4 & 15) * 4;
      float4 qv = *(const float4*)&qb[d][l0];
      f32x4 ov;
      float dx = qv.x - xv.x, dy = qv.y - xv.y, dz = qv.z - xv.z, dw_ = qv.w - xv.w;
      ov.x = xv.x + dx; ov.y = xv.y + dy; ov.z = xv.z + dz; ov.w = xv.w + dw_;
      __builtin_nontemporal_store(ov, (f32x4*)&op[f4 * 4]);  // x + (q - x), streamed
      ls = fmaf(dx, dx, ls); ls = fmaf(dy, dy, ls);
      ls = fmaf(dz, dz, ls); ls = fmaf(dw_, dw_, ls);
    }
    float* encp = out_enc + (size_t)b * 32768;
#pragma unroll
    for (int i = 0; i < 32; ++i) {
      int f4 = t + i * 256;
      int e = f4 * 4;
      int k = e >> 6, l0 = e & 63;
      f32x4 v;
      v.x = (lidx[l0 + 0] == k) ? 1.f : 0.f;
      v.y = (lidx[l0 + 1] == k) ? 1.f : 0.f;
      v.z = (lidx[l0 + 2] == k) ? 1.f : 0.f;
      v.w = (lidx[l0 + 3] == k) ? 1.f : 0.f;
      __builtin_nontemporal_store(v, (f32x4*)&encp[e]);
    }
#pragma unroll
    for (int off = 32; off > 0; off >>= 1) ls += __shfl_down(ls, off, 64);
    if ((t & 63) == 0) wsumS[t >> 6] = (double)ls;
    __syncthreads();
    if (t == 0) unsafeAtomicAdd(lossAcc, wsumS[0] + wsumS[1] + wsumS[2] + wsumS[3]);
  }
}

// ---------------- K4: cs + EMA (k=blk) | perplexity (blk>=512) + loss ----------------
__global__ __launch_bounds__(256) void kemafinal(const float* __restrict__ cluster,
                                                 const float* __restrict__ countsT,
                                                 const float* __restrict__ dw,
                                                 const float* __restrict__ emb,
                                                 const float* __restrict__ dwT,
                                                 const double* __restrict__ lossAcc,
                                                 float* __restrict__ out_cs,
                                                 float* __restrict__ out_emb,
                                                 float* __restrict__ out_dwb,
                                                 float* __restrict__ out_loss,
                                                 float* __restrict__ out_perp) {
  const int t = threadIdx.x;
  if (blockIdx.x >= 512) {
    const int l = blockIdx.x - 512;
    if (t < 64) {
      float s = 0.f;
#pragma unroll
      for (int i = 0; i < 8; ++i) {
        int k = t * 8 + i;
        float p = countsT[l * 512 + k] * (1.0f / 1024.0f);  // exact: /2^10
        s = __fadd_rn(s, __fmul_rn(p, logf(__fadd_rn(p, 1e-10f))));
      }
#pragma unroll
      for (int off = 32; off > 0; off >>= 1) s += __shfl_down(s, off, 64);
      if (t == 0) out_perp[l] = expf(-s) * (1.0f / 512.0f);
    }
    if (blockIdx.x == 512 && t == 64)
      out_loss[0] = (float)(lossAcc[0] / 4194304.0);  // mean over B*D*L
    return;
  }
  const int k = blockIdx.x;
  __shared__ float dwS[64][65];
  __shared__ float csS[64];
  __shared__ float nS;
  const float* sp = dwT + (size_t)k * 4096;
#pragma unroll
  for (int i = 0; i < 4; ++i) {
    int f4 = t + i * 256;
    float4 v = *(const float4*)&sp[f4 * 4];
    int l = f4 >> 4, d0 = (f4 & 15) * 4;
    dwS[l][d0] = v.x; dwS[l][d0 + 1] = v.y; dwS[l][d0 + 2] = v.z; dwS[l][d0 + 3] = v.w;
  }
  const float* cp = cluster + k * 64;
  if (t == 0) {
    float n = 0.f;
#pragma unroll
    for (int l = 0; l < 64; ++l) n = __fadd_rn(n, cp[l]);
    nS = __fadd_rn(n, 1e-06f);
  }
  __syncthreads();
  if (t < 64) {
    const float n = nS;
    const float denom = __fadd_rn(n, 0.000512f);  // n + K*EPS
    float t1 = __fadd_rn(cp[t], 1e-06f);
    float r = __fdiv_rn(t1, denom);
    float r2 = __fmul_rn(r, n);
    float cs = __fadd_rn(__fmul_rn(0.99f, r2), __fmul_rn(0.01f, countsT[t * 512 + k]));
    csS[t] = cs;
    out_cs[k * 64 + t] = cs;
  }
  __syncthreads();
  const int l = t & 63;
  const int dlane = t >> 6;
#pragma unroll
  for (int r = 0; r < 16; ++r) {
    int d = r * 4 + dlane;
    int g = d * 32768 + k * 64 + l;
    float batch = dwS[l][d];
    float buf = 0.99f * dw[g] + 0.01f * (batch / csS[l]);
    out_dwb[g] = buf;
    out_emb[g] = 0.99f * emb[g] + 0.01f * buf;
  }
}

extern "C" void kernel_launch(void* const* d_in, const int* in_sizes, int n_in,
                              void* d_out, int out_size, void* d_ws, size_t ws_size,
                              hipStream_t stream) {
  (void)in_sizes; (void)n_in; (void)out_size; (void)ws_size;
  const float* x    = (const float*)d_in[0];
  const float* emb  = (const float*)d_in[1];
  const float* dw   = (const float*)d_in[2];
  const float* clus = (const float*)d_in[3];

  float* out = (float*)d_out;
  float* out_q    = out;                 // 4194304
  float* out_enc  = out + 4194304;       // 33554432
  float* out_loss = out + 37748736;      // 1
  float* out_perp = out + 37748737;      // 64
  float* out_emb  = out + 37748801;      // 2097152
  float* out_dwb  = out + 39845953;      // 2097152
  float* out_cs   = out + 41943105;      // 32768

  float* wsf = (float*)d_ws;
  float*  dwT     = wsf;                      // 2,097,152 floats (8 MB)
  float*  countsT = wsf + 2097152;            // 32768 (zeroed in K1)
  float*  eT      = wsf + 2129920;            // 2,097,152 (8 MB)
  float*  e2T     = wsf + 4227072;            // 32768
  int*    idxb    = (int*)(wsf + 4259840);    // 65536
  int*    idxT    = (int*)(wsf + 4325376);    // 65536
  double* lossA   = (double*)(wsf + 4390912); // 8 B (zeroed in K1)
  float*  xT      = wsf + 4456448;            // 4,194,304 floats (16 MB)

  ktransAll<<<1536, 256, 0, stream>>>(emb, x, eT, e2T, xT, countsT, lossA);
  kargmin_s2<<<dim3(64, 16), 256, 0, stream>>>(xT, eT, e2T, idxb, idxT, countsT);
  kdwgather<<<1280, 256, 0, stream>>>(x, xT, eT, idxb, idxT, dwT, out_q, out_enc, lossA);
  kemafinal<<<576, 256, 0, stream>>>(clus, countsT, dw, emb, dwT, lossA,
                                     out_cs, out_emb, out_dwb, out_loss, out_perp);
}

// Round 15
// 159.664 us; speedup vs baseline: 1.9216x; 1.0339x over previous
//
#include <hip/hip_runtime.h>

// Problem constants: B=1024, D=64, K=512, L=64 (h*w=8*8)
// x (B,D,L); emb/dw (D,K,L); eT (L,K,D); e2T (L,K); countsT (L,K);
// dwT (K,L,D); xT (L,B,D) in WS; idxb (B,L); idxT (L,B)
// K2 (r15): r13/r14's x-array lived in SCRATCH (SROA cannot promote a
// loop-indexed array; 64MB scratch -> 16.5GB HBM refetch). Fix: 16 NAMED
// f32x4 registers + macro-expanded FMA chain. d-ascending chain per (b,l,k)
// is statement-identical -> bit-identical d2 to rounds 7-14.

typedef float f32x4 __attribute__((ext_vector_type(4)));

// ---------------- K1: fused emb transpose + e2 | x transpose | zero counts/loss ----------------
__global__ __launch_bounds__(256) void ktransAll(const float* __restrict__ emb,
                                                 const float* __restrict__ x,
                                                 float* __restrict__ eT,
                                                 float* __restrict__ e2T,
                                                 float* __restrict__ xT,
                                                 float* __restrict__ countsT,
                                                 double* __restrict__ lossAcc) {
  const int t = threadIdx.x;
  __shared__ float s[64][65];
  if (blockIdx.x < 512) {
    const int k = blockIdx.x;
#pragma unroll
    for (int i = 0; i < 16; ++i) {
      int e = t + i * 256;
      int d = e >> 6, l = e & 63;
      s[d][l] = emb[d * 32768 + k * 64 + l];
    }
    __syncthreads();
    if (t < 64) {
      float s2 = 0.f;
#pragma unroll
      for (int d = 0; d < 64; ++d) {
        float v = s[d][t];
        s2 = __fadd_rn(s2, __fmul_rn(v, v));  // round(v*v), sequential-d sum like ref
      }
      e2T[t * 512 + k] = s2;
      countsT[k * 64 + t] = 0.f;   // all 32768 entries zeroed across 512 blocks
    }
    if (k == 0 && t == 0) lossAcc[0] = 0.0;
#pragma unroll
    for (int i = 0; i < 4; ++i) {
      int j = t + i * 256;
      int l = j >> 4, d0 = (j & 15) * 4;
      float4 w;
      w.x = s[d0][l]; w.y = s[d0 + 1][l]; w.z = s[d0 + 2][l]; w.w = s[d0 + 3][l];
      *(float4*)&eT[(l * 512 + k) * 64 + d0] = w;
    }
  } else {
    const int b = blockIdx.x - 512;
    const float* xp = x + b * 4096;
#pragma unroll
    for (int i = 0; i < 4; ++i) {
      int f4 = t + i * 256;
      float4 v = *(const float4*)&xp[f4 * 4];
      int d = f4 >> 4, l0 = (f4 & 15) * 4;
      s[d][l0] = v.x; s[d][l0 + 1] = v.y; s[d][l0 + 2] = v.z; s[d][l0 + 3] = v.w;
    }
    __syncthreads();
#pragma unroll
    for (int i = 0; i < 4; ++i) {
      int j = t + i * 256;
      int l = j >> 4, d0 = (j & 15) * 4;
      float4 w;
      w.x = s[d0][l]; w.y = s[d0 + 1][l]; w.z = s[d0 + 2][l]; w.w = s[d0 + 3][l];
      *(float4*)&xT[((size_t)l * 1024 + b) * 64 + d0] = w;
    }
  }
}

// ---------------- K2: argmin GEMM — x in 16 NAMED VGPR vectors, e via scalar loads ----------------
// grid (64, 16): x = l (XCD = l%8), y = b-tile of 64 (lane = b row).
// 4 waves/block: wave w owns k-quarter [w*128, w*128+128).
__global__ __launch_bounds__(256) void kargmin_s3(const float* __restrict__ xT,
                                                  const float* __restrict__ eT,
                                                  const float* __restrict__ e2T,
                                                  int* __restrict__ idxout,
                                                  int* __restrict__ idxTout,
                                                  float* __restrict__ countsT) {
  const int l = blockIdx.x;
  const int b0 = blockIdx.y * 64;
  const int t = threadIdx.x;
  const int lane = t & 63;
  const int w = __builtin_amdgcn_readfirstlane(t >> 6);  // force wave-uniform
  __shared__ float rv[4][64];
  __shared__ float rkf[4][64];

  // x row (b0+lane, l): 16 NAMED f32x4 -> unconditionally promoted to VGPRs
  const f32x4* xp = (const f32x4*)(xT + ((size_t)l * 1024 + b0 + lane) * 64);
  const f32x4 x0 = xp[0],  x1 = xp[1],  x2 = xp[2],  x3 = xp[3];
  const f32x4 x4 = xp[4],  x5 = xp[5],  x6 = xp[6],  x7 = xp[7];
  const f32x4 x8 = xp[8],  x9 = xp[9],  x10 = xp[10], x11 = xp[11];
  const f32x4 x12 = xp[12], x13 = xp[13], x14 = xp[14], x15 = xp[15];

  const float* __restrict__ ew = eT + ((size_t)l * 512 + w * 128) * 64;  // uniform base
  const float* __restrict__ e2w = e2T + l * 512 + w * 128;               // uniform base
  float bestv = 3.4e38f;
  int bestk = 0;

#define STEP(i)                                  \
  a0 = fmaf(x##i.x, e0[4 * i + 0], a0);          \
  a0 = fmaf(x##i.y, e0[4 * i + 1], a0);          \
  a0 = fmaf(x##i.z, e0[4 * i + 2], a0);          \
  a0 = fmaf(x##i.w, e0[4 * i + 3], a0);          \
  a1 = fmaf(x##i.x, e1[4 * i + 0], a1);          \
  a1 = fmaf(x##i.y, e1[4 * i + 1], a1);          \
  a1 = fmaf(x##i.z, e1[4 * i + 2], a1);          \
  a1 = fmaf(x##i.w, e1[4 * i + 3], a1);

  for (int kk = 0; kk < 128; kk += 2) {      // kk uniform loop counter
    const float* e0 = ew + kk * 64;          // uniform -> scalar loads
    const float* e1 = e0 + 64;
    float a0 = 0.f, a1 = 0.f;
    STEP(0)  STEP(1)  STEP(2)  STEP(3)       // d ascending: chain identical to r7-r14
    STEP(4)  STEP(5)  STEP(6)  STEP(7)
    STEP(8)  STEP(9)  STEP(10) STEP(11)
    STEP(12) STEP(13) STEP(14) STEP(15)
    float d0 = fmaf(-2.0f, a0, e2w[kk]);     // e2 - 2*xe, single rounding
    float d1 = fmaf(-2.0f, a1, e2w[kk + 1]);
    if (d0 < bestv) { bestv = d0; bestk = w * 128 + kk; }      // ascending k:
    if (d1 < bestv) { bestv = d1; bestk = w * 128 + kk + 1; }  // strict < keeps lowest
  }
#undef STEP
  rv[w][lane] = bestv;
  rkf[w][lane] = (float)bestk;   // exact for k<512
  __syncthreads();
  if (t < 64) {
    float bv = rv[0][t];
    int bk = (int)rkf[0][t];
#pragma unroll
    for (int g = 1; g < 4; ++g) {
      float v = rv[g][t];
      int kk2 = (int)rkf[g][t];
      if (v < bv || (v == bv && kk2 < bk)) { bv = v; bk = kk2; }
    }
    idxout[(b0 + t) * 64 + l] = bk;
    idxTout[l * 1024 + b0 + t] = bk;
    unsafeAtomicAdd(&countsT[l * 512 + bk], 1.0f);  // integer counts: exact any order
  }
}

// ---------------- K3: role-split — dw-accumulate (256 blocks) + gather (1024 blocks) ----------------
__global__ __launch_bounds__(256) void kdwgather(const float* __restrict__ x,
                                                 const float* __restrict__ xT,
                                                 const float* __restrict__ eT,
                                                 const int* __restrict__ idxb,
                                                 const int* __restrict__ idxT,
                                                 float* __restrict__ dwT,
                                                 float* __restrict__ out_q,
                                                 float* __restrict__ out_enc,
                                                 double* __restrict__ lossAcc) {
  const int t = threadIdx.x;
  __shared__ float SM[8192];   // 32 KB, reused per role
  if (blockIdx.x < 256) {
    const int l = blockIdx.x & 63;
    const int kq = (blockIdx.x >> 6) * 128;
    float* acc = SM;  // 128 k x 64 d
#pragma unroll
    for (int i = 0; i < 32; ++i) acc[t + i * 256] = 0.f;
    const int w = t >> 6, lane = t & 63;
    __syncthreads();
    const int* idxl = idxT + l * 1024;
    const float* xTl = xT + (size_t)l * 65536;
    for (int c = 0; c < 4; ++c) {
      const int base = w * 256 + c * 64;
      const int myidx = idxl[base + lane];
      for (int jj = 0; jj < 64; jj += 8) {
        int ks[8]; float vs[8];
#pragma unroll
        for (int u = 0; u < 8; ++u) ks[u] = __shfl(myidx, jj + u, 64) - kq;  // wave-uniform
#pragma unroll
        for (int u = 0; u < 8; ++u)
          if ((unsigned)ks[u] < 128u)
            vs[u] = xTl[(size_t)(base + jj + u) * 64 + lane];  // coalesced
#pragma unroll
        for (int u = 0; u < 8; ++u)
          if ((unsigned)ks[u] < 128u)
            atomicAdd(&acc[(ks[u] << 6) + lane], vs[u]);  // ds_add_f32
      }
    }
    __syncthreads();
#pragma unroll
    for (int i = 0; i < 32; ++i) {
      int e = t + i * 256;
      int k = e >> 6, d = e & 63;
      dwT[((size_t)(kq + k) * 64 + l) * 64 + d] = acc[e];
    }
  } else {
    const int b = blockIdx.x - 256;
    float (*qb)[68] = (float (*)[68])SM;    // 64x68 = 4352
    int* lidx = (int*)(SM + 4352);          // 64
    double* wsumS = (double*)(SM + 4432);   // 8-aligned
    if (t < 64) lidx[t] = idxb[b * 64 + t];
    __syncthreads();
    const int l = t >> 2, qd = (t & 3) * 16;
    const int kse = lidx[l];
    const float* ep = eT + (l * 512 + kse) * 64 + qd;
#pragma unroll
    for (int j = 0; j < 4; ++j) {
      float4 v = *(const float4*)&ep[j * 4];
      qb[qd + j * 4 + 0][l] = v.x;
      qb[qd + j * 4 + 1][l] = v.y;
      qb[qd + j * 4 + 2][l] = v.z;
      qb[qd + j * 4 + 3][l] = v.w;
    }
    __syncthreads();
    float ls = 0.f;
    const float* xp = x + b * 4096;
    float* op = out_q + b * 4096;
#pragma unroll
    for (int i = 0; i < 4; ++i) {
      int f4 = t + i * 256;
      float4 xv = *(const float4*)&xp[f4 * 4];
      int d = f4 >> 4, l0 = (f4 & 15) * 4;
      float4 qv = *(const float4*)&qb[d][l0];
      f32x4 ov;
      float dx = qv.x - xv.x, dy = qv.y - xv.y, dz = qv.z - xv.z, dw_ = qv.w - xv.w;
      ov.x = xv.x + dx; ov.y = xv.y + dy; ov.z = xv.z + dz; ov.w = xv.w + dw_;
      __builtin_nontemporal_store(ov, (f32x4*)&op[f4 * 4]);  // x + (q - x), streamed
      ls = fmaf(dx, dx, ls); ls = fmaf(dy, dy, ls);
      ls = fmaf(dz, dz, ls); ls = fmaf(dw_, dw_, ls);
    }
    float* encp = out_enc + (size_t)b * 32768;
#pragma unroll
    for (int i = 0; i < 32; ++i) {
      int f4 = t + i * 256;
      int e = f4 * 4;
      int k = e >> 6, l0 = e & 63;
      f32x4 v;
      v.x = (lidx[l0 + 0] == k) ? 1.f : 0.f;
      v.y = (lidx[l0 + 1] == k) ? 1.f : 0.f;
      v.z = (lidx[l0 + 2] == k) ? 1.f : 0.f;
      v.w = (lidx[l0 + 3] == k) ? 1.f : 0.f;
      __builtin_nontemporal_store(v, (f32x4*)&encp[e]);
    }
#pragma unroll
    for (int off = 32; off > 0; off >>= 1) ls += __shfl_down(ls, off, 64);
    if ((t & 63) == 0) wsumS[t >> 6] = (double)ls;
    __syncthreads();
    if (t == 0) unsafeAtomicAdd(lossAcc, wsumS[0] + wsumS[1] + wsumS[2] + wsumS[3]);
  }
}

// ---------------- K4: cs + EMA (k=blk) | perplexity (blk>=512) + loss ----------------
__global__ __launch_bounds__(256) void kemafinal(const float* __restrict__ cluster,
                                                 const float* __restrict__ countsT,
                                                 const float* __restrict__ dw,
                                                 const float* __restrict__ emb,
                                                 const float* __restrict__ dwT,
                                                 const double* __restrict__ lossAcc,
                                                 float* __restrict__ out_cs,
                                                 float* __restrict__ out_emb,
                                                 float* __restrict__ out_dwb,
                                                 float* __restrict__ out_loss,
                                                 float* __restrict__ out_perp) {
  const int t = threadIdx.x;
  if (blockIdx.x >= 512) {
    const int l = blockIdx.x - 512;
    if (t < 64) {
      float s = 0.f;
#pragma unroll
      for (int i = 0; i < 8; ++i) {
        int k = t * 8 + i;
        float p = countsT[l * 512 + k] * (1.0f / 1024.0f);  // exact: /2^10
        s = __fadd_rn(s, __fmul_rn(p, logf(__fadd_rn(p, 1e-10f))));
      }
#pragma unroll
      for (int off = 32; off > 0; off >>= 1) s += __shfl_down(s, off, 64);
      if (t == 0) out_perp[l] = expf(-s) * (1.0f / 512.0f);
    }
    if (blockIdx.x == 512 && t == 64)
      out_loss[0] = (float)(lossAcc[0] / 4194304.0);  // mean over B*D*L
    return;
  }
  const int k = blockIdx.x;
  __shared__ float dwS[64][65];
  __shared__ float csS[64];
  __shared__ float nS;
  const float* sp = dwT + (size_t)k * 4096;
#pragma unroll
  for (int i = 0; i < 4; ++i) {
    int f4 = t + i * 256;
    float4 v = *(const float4*)&sp[f4 * 4];
    int l = f4 >> 4, d0 = (f4 & 15) * 4;
    dwS[l][d0] = v.x; dwS[l][d0 + 1] = v.y; dwS[l][d0 + 2] = v.z; dwS[l][d0 + 3] = v.w;
  }
  const float* cp = cluster + k * 64;
  if (t == 0) {
    float n = 0.f;
#pragma unroll
    for (int l = 0; l < 64; ++l) n = __fadd_rn(n, cp[l]);
    nS = __fadd_rn(n, 1e-06f);
  }
  __syncthreads();
  if (t < 64) {
    const float n = nS;
    const float denom = __fadd_rn(n, 0.000512f);  // n + K*EPS
    float t1 = __fadd_rn(cp[t], 1e-06f);
    float r = __fdiv_rn(t1, denom);
    float r2 = __fmul_rn(r, n);
    float cs = __fadd_rn(__fmul_rn(0.99f, r2), __fmul_rn(0.01f, countsT[t * 512 + k]));
    csS[t] = cs;
    out_cs[k * 64 + t] = cs;
  }
  __syncthreads();
  const int l = t & 63;
  const int dlane = t >> 6;
#pragma unroll
  for (int r = 0; r < 16; ++r) {
    int d = r * 4 + dlane;
    int g = d * 32768 + k * 64 + l;
    float batch = dwS[l][d];
    float buf = 0.99f * dw[g] + 0.01f * (batch / csS[l]);
    out_dwb[g] = buf;
    out_emb[g] = 0.99f * emb[g] + 0.01f * buf;
  }
}

extern "C" void kernel_launch(void* const* d_in, const int* in_sizes, int n_in,
                              void* d_out, int out_size, void* d_ws, size_t ws_size,
                              hipStream_t stream) {
  (void)in_sizes; (void)n_in; (void)out_size; (void)ws_size;
  const float* x    = (const float*)d_in[0];
  const float* emb  = (const float*)d_in[1];
  const float* dw   = (const float*)d_in[2];
  const float* clus = (const float*)d_in[3];

  float* out = (float*)d_out;
  float* out_q    = out;                 // 4194304
  float* out_enc  = out + 4194304;       // 33554432
  float* out_loss = out + 37748736;      // 1
  float* out_perp = out + 37748737;      // 64
  float* out_emb  = out + 37748801;      // 2097152
  float* out_dwb  = out + 39845953;      // 2097152
  float* out_cs   = out + 41943105;      // 32768

  float* wsf = (float*)d_ws;
  float*  dwT     = wsf;                      // 2,097,152 floats (8 MB)
  float*  countsT = wsf + 2097152;            // 32768 (zeroed in K1)
  float*  eT      = wsf + 2129920;            // 2,097,152 (8 MB)
  float*  e2T     = wsf + 4227072;            // 32768
  int*    idxb    = (int*)(wsf + 4259840);    // 65536
  int*    idxT    = (int*)(wsf + 4325376);    // 65536
  double* lossA   = (double*)(wsf + 4390912); // 8 B (zeroed in K1)
  float*  xT      = wsf + 4456448;            // 4,194,304 floats (16 MB)

  ktransAll<<<1536, 256, 0, stream>>>(emb, x, eT, e2T, xT, countsT, lossA);
  kargmin_s3<<<dim3(64, 16), 256, 0, stream>>>(xT, eT, e2T, idxb, idxT, countsT);
  kdwgather<<<1280, 256, 0, stream>>>(x, xT, eT, idxb, idxT, dwT, out_q, out_enc, lossA);
  kemafinal<<<576, 256, 0, stream>>>(clus, countsT, dw, emb, dwT, lossA,
                                     out_cs, out_emb, out_dwb, out_loss, out_perp);
}

// Round 16
// 143.067 us; speedup vs baseline: 2.1446x; 1.1160x over previous
//
#include <hip/hip_runtime.h>

// Problem constants: B=1024, D=64, K=512, L=64 (h*w=8*8)
// x (B,D,L); emb/dw (D,K,L); eT (L,K,D); e2T (L,K); countsT (L,K);
// dwT (K,L,D); xT (L,B,D) in WS; idxb (B,L); idxT (L,B)
// r16 = verified r11 pipeline; K2 gains T14 async-stage (prefetch next es
// chunk into registers during compute; ds_write after barrier). r13-15's
// scalar-operand design abandoned: compiler sinks x-loads into the loop
// (VGPR=36), L2-latency-bound at ~100us. ERRATA: FETCH_SIZE is KB not GB.

typedef float f32x4 __attribute__((ext_vector_type(4)));

// ---------------- K1: fused emb transpose + e2 | x transpose | zero counts/loss ----------------
__global__ __launch_bounds__(256) void ktransAll(const float* __restrict__ emb,
                                                 const float* __restrict__ x,
                                                 float* __restrict__ eT,
                                                 float* __restrict__ e2T,
                                                 float* __restrict__ xT,
                                                 float* __restrict__ countsT,
                                                 double* __restrict__ lossAcc) {
  const int t = threadIdx.x;
  __shared__ float s[64][65];
  if (blockIdx.x < 512) {
    const int k = blockIdx.x;
#pragma unroll
    for (int i = 0; i < 16; ++i) {
      int e = t + i * 256;
      int d = e >> 6, l = e & 63;
      s[d][l] = emb[d * 32768 + k * 64 + l];
    }
    __syncthreads();
    if (t < 64) {
      float s2 = 0.f;
#pragma unroll
      for (int d = 0; d < 64; ++d) {
        float v = s[d][t];
        s2 = __fadd_rn(s2, __fmul_rn(v, v));  // round(v*v), sequential-d sum like ref
      }
      e2T[t * 512 + k] = s2;
      countsT[k * 64 + t] = 0.f;   // all 32768 entries zeroed across 512 blocks
    }
    if (k == 0 && t == 0) lossAcc[0] = 0.0;
#pragma unroll
    for (int i = 0; i < 4; ++i) {
      int j = t + i * 256;
      int l = j >> 4, d0 = (j & 15) * 4;
      float4 w;
      w.x = s[d0][l]; w.y = s[d0 + 1][l]; w.z = s[d0 + 2][l]; w.w = s[d0 + 3][l];
      *(float4*)&eT[(l * 512 + k) * 64 + d0] = w;
    }
  } else {
    const int b = blockIdx.x - 512;
    const float* xp = x + b * 4096;
#pragma unroll
    for (int i = 0; i < 4; ++i) {
      int f4 = t + i * 256;
      float4 v = *(const float4*)&xp[f4 * 4];
      int d = f4 >> 4, l0 = (f4 & 15) * 4;
      s[d][l0] = v.x; s[d][l0 + 1] = v.y; s[d][l0 + 2] = v.z; s[d][l0 + 3] = v.w;
    }
    __syncthreads();
#pragma unroll
    for (int i = 0; i < 4; ++i) {
      int j = t + i * 256;
      int l = j >> 4, d0 = (j & 15) * 4;
      float4 w;
      w.x = s[d0][l]; w.y = s[d0 + 1][l]; w.z = s[d0 + 2][l]; w.w = s[d0 + 3][l];
      *(float4*)&xT[((size_t)l * 1024 + b) * 64 + d0] = w;
    }
  }
}

// ---------------- K2: argmin distance GEMM (r11 LDS design + T14 es prefetch) ----------------
// grid (64, 8): x = l (XCD = l%8 -> eT slab L2-local), y = b-tile of 128.
// 256 threads: bg = t&15, kg = t>>4. 4 chunks of 128 k-cols; LDS ~70KB -> 2 blocks/CU.
__global__ __launch_bounds__(256, 2) void kargmin(const float* __restrict__ xT,
                                                  const float* __restrict__ eT,
                                                  const float* __restrict__ e2T,
                                                  int* __restrict__ idxout,
                                                  int* __restrict__ idxTout,
                                                  float* __restrict__ countsT) {
  const int l = blockIdx.x;
  const int b0 = blockIdx.y * 128;
  const int t = threadIdx.x;
  __shared__ float xs[128][68];
  __shared__ float es[128][68];
  __shared__ float e2s[128];

  // T14: prefetch chunk-0 es into registers (latency overlaps xs staging)
  float4 pf[8];
  {
    const float* src = eT + (size_t)l * 512 * 64;
#pragma unroll
    for (int i = 0; i < 8; ++i) pf[i] = *(const float4*)&src[(t + i * 256) * 4];
  }
  float e2pf = (t < 128) ? e2T[l * 512 + t] : 0.f;

  const float* xsrc = xT + ((size_t)l * 1024 + b0) * 64;
#pragma unroll
  for (int i = 0; i < 8; ++i) {
    int f4 = t + i * 256;             // 2048 float4 = 128x64, fully coalesced
    int r = f4 >> 4;
    int c = (f4 & 15) * 4;
    *(float4*)&xs[r][c] = *(const float4*)&xsrc[f4 * 4];
  }
  const int bg = t & 15;
  const int kg = t >> 4;
  float bestv[8];
  int bestk[8];
#pragma unroll
  for (int i = 0; i < 8; ++i) { bestv[i] = 3.4e38f; bestk[i] = 0; }

  for (int chunk = 0; chunk < 4; ++chunk) {
    if (chunk > 0) __syncthreads();   // prev compute done before es overwrite
    // commit prefetched es to LDS (vmcnt wait here was hidden under prev compute)
#pragma unroll
    for (int i = 0; i < 8; ++i) {
      int f4 = t + i * 256;
      int r = f4 >> 4;
      int c = (f4 & 15) * 4;
      *(float4*)&es[r][c] = pf[i];
    }
    if (t < 128) e2s[t] = e2pf;
    if (chunk < 3) {                  // issue next-chunk prefetch before compute
      const float* src = eT + ((size_t)l * 512 + (chunk + 1) * 128) * 64;
#pragma unroll
      for (int i = 0; i < 8; ++i) pf[i] = *(const float4*)&src[(t + i * 256) * 4];
      e2pf = (t < 128) ? e2T[l * 512 + (chunk + 1) * 128 + t] : 0.f;
    }
    __syncthreads();

    float acc[8][8];
#pragma unroll
    for (int i = 0; i < 8; ++i)
#pragma unroll
      for (int j = 0; j < 8; ++j) acc[i][j] = 0.f;

    for (int d4 = 0; d4 < 16; ++d4) {
      float4 xv[8], ev[8];
#pragma unroll
      for (int i = 0; i < 8; ++i) xv[i] = *(const float4*)&xs[bg + i * 16][d4 * 4];
#pragma unroll
      for (int j = 0; j < 8; ++j) ev[j] = *(const float4*)&es[kg + j * 16][d4 * 4];
#pragma unroll
      for (int i = 0; i < 8; ++i)
#pragma unroll
        for (int j = 0; j < 8; ++j) {
          acc[i][j] = fmaf(xv[i].x, ev[j].x, acc[i][j]);
          acc[i][j] = fmaf(xv[i].y, ev[j].y, acc[i][j]);
          acc[i][j] = fmaf(xv[i].z, ev[j].z, acc[i][j]);
          acc[i][j] = fmaf(xv[i].w, ev[j].w, acc[i][j]);
        }
    }
#pragma unroll
    for (int j = 0; j < 8; ++j) {
      int kk = kg + j * 16;
      int kglob = chunk * 128 + kk;
      float e2v = e2s[kk];
#pragma unroll
      for (int i = 0; i < 8; ++i) {
        float d2 = fmaf(-2.0f, acc[i][j], e2v);  // e2 - 2*xe, single rounding
        if (d2 < bestv[i] || (d2 == bestv[i] && kglob < bestk[i])) {
          bestv[i] = d2; bestk[i] = kglob;
        }
      }
    }
  }
  __syncthreads();
  // cross-kg reduction; reuse es (vals) and xs (k as float, exact for k<512)
  float* rv = &es[0][0];
  float* rkf = &xs[0][0];
#pragma unroll
  for (int i = 0; i < 8; ++i) {
    int bl = bg + i * 16;
    rv[bl * 16 + kg] = bestv[i];
    rkf[bl * 16 + kg] = (float)bestk[i];
  }
  __syncthreads();
  if (t < 128) {
    float bv = rv[t * 16];
    int bk = (int)rkf[t * 16];
#pragma unroll
    for (int g = 1; g < 16; ++g) {
      float v = rv[t * 16 + g];
      int kk = (int)rkf[t * 16 + g];
      if (v < bv || (v == bv && kk < bk)) { bv = v; bk = kk; }
    }
    idxout[(b0 + t) * 64 + l] = bk;
    idxTout[l * 1024 + b0 + t] = bk;
    unsafeAtomicAdd(&countsT[l * 512 + bk], 1.0f);  // integer counts: exact any order
  }
}

// ---------------- K3: role-split — dw-accumulate (256 blocks) + gather (1024 blocks) ----------------
__global__ __launch_bounds__(256) void kdwgather(const float* __restrict__ x,
                                                 const float* __restrict__ xT,
                                                 const float* __restrict__ eT,
                                                 const int* __restrict__ idxb,
                                                 const int* __restrict__ idxT,
                                                 float* __restrict__ dwT,
                                                 float* __restrict__ out_q,
                                                 float* __restrict__ out_enc,
                                                 double* __restrict__ lossAcc) {
  const int t = threadIdx.x;
  __shared__ float SM[8192];   // 32 KB, reused per role
  if (blockIdx.x < 256) {
    const int l = blockIdx.x & 63;
    const int kq = (blockIdx.x >> 6) * 128;
    float* acc = SM;  // 128 k x 64 d
#pragma unroll
    for (int i = 0; i < 32; ++i) acc[t + i * 256] = 0.f;
    const int w = t >> 6, lane = t & 63;
    __syncthreads();
    const int* idxl = idxT + l * 1024;
    const float* xTl = xT + (size_t)l * 65536;
    for (int c = 0; c < 4; ++c) {
      const int base = w * 256 + c * 64;
      const int myidx = idxl[base + lane];
      for (int jj = 0; jj < 64; jj += 8) {
        int ks[8]; float vs[8];
#pragma unroll
        for (int u = 0; u < 8; ++u) ks[u] = __shfl(myidx, jj + u, 64) - kq;  // wave-uniform
#pragma unroll
        for (int u = 0; u < 8; ++u)
          if ((unsigned)ks[u] < 128u)
            vs[u] = xTl[(size_t)(base + jj + u) * 64 + lane];  // coalesced
#pragma unroll
        for (int u = 0; u < 8; ++u)
          if ((unsigned)ks[u] < 128u)
            atomicAdd(&acc[(ks[u] << 6) + lane], vs[u]);  // ds_add_f32
      }
    }
    __syncthreads();
#pragma unroll
    for (int i = 0; i < 32; ++i) {
      int e = t + i * 256;
      int k = e >> 6, d = e & 63;
      dwT[((size_t)(kq + k) * 64 + l) * 64 + d] = acc[e];
    }
  } else {
    const int b = blockIdx.x - 256;
    float (*qb)[68] = (float (*)[68])SM;    // 64x68 = 4352
    int* lidx = (int*)(SM + 4352);          // 64
    double* wsumS = (double*)(SM + 4432);   // 8-aligned
    if (t < 64) lidx[t] = idxb[b * 64 + t];
    __syncthreads();
    const int l = t >> 2, qd = (t & 3) * 16;
    const int kse = lidx[l];
    const float* ep = eT + (l * 512 + kse) * 64 + qd;
#pragma unroll
    for (int j = 0; j < 4; ++j) {
      float4 v = *(const float4*)&ep[j * 4];
      qb[qd + j * 4 + 0][l] = v.x;
      qb[qd + j * 4 + 1][l] = v.y;
      qb[qd + j * 4 + 2][l] = v.z;
      qb[qd + j * 4 + 3][l] = v.w;
    }
    __syncthreads();
    float ls = 0.f;
    const float* xp = x + b * 4096;
    float* op = out_q + b * 4096;
#pragma unroll
    for (int i = 0; i < 4; ++i) {
      int f4 = t + i * 256;
      float4 xv = *(const float4*)&xp[f4 * 4];
      int d = f4 >> 4, l0 = (f4 & 15) * 4;
      float4 qv = *(const float4*)&qb[d][l0];
      f32x4 ov;
      float dx = qv.x - xv.x, dy = qv.y - xv.y, dz = qv.z - xv.z, dw_ = qv.w - xv.w;
      ov.x = xv.x + dx; ov.y = xv.y + dy; ov.z = xv.z + dz; ov.w = xv.w + dw_;
      __builtin_nontemporal_store(ov, (f32x4*)&op[f4 * 4]);  // x + (q - x), streamed
      ls = fmaf(dx, dx, ls); ls = fmaf(dy, dy, ls);
      ls = fmaf(dz, dz, ls); ls = fmaf(dw_, dw_, ls);
    }
    float* encp = out_enc + (size_t)b * 32768;
#pragma unroll
    for (int i = 0; i < 32; ++i) {
      int f4 = t + i * 256;
      int e = f4 * 4;
      int k = e >> 6, l0 = e & 63;
      f32x4 v;
      v.x = (lidx[l0 + 0] == k) ? 1.f : 0.f;
      v.y = (lidx[l0 + 1] == k) ? 1.f : 0.f;
      v.z = (lidx[l0 + 2] == k) ? 1.f : 0.f;
      v.w = (lidx[l0 + 3] == k) ? 1.f : 0.f;
      __builtin_nontemporal_store(v, (f32x4*)&encp[e]);
    }
#pragma unroll
    for (int off = 32; off > 0; off >>= 1) ls += __shfl_down(ls, off, 64);
    if ((t & 63) == 0) wsumS[t >> 6] = (double)ls;
    __syncthreads();
    if (t == 0) unsafeAtomicAdd(lossAcc, wsumS[0] + wsumS[1] + wsumS[2] + wsumS[3]);
  }
}

// ---------------- K4: cs + EMA (k=blk) | perplexity (blk>=512) + loss ----------------
__global__ __launch_bounds__(256) void kemafinal(const float* __restrict__ cluster,
                                                 const float* __restrict__ countsT,
                                                 const float* __restrict__ dw,
                                                 const float* __restrict__ emb,
                                                 const float* __restrict__ dwT,
                                                 const double* __restrict__ lossAcc,
                                                 float* __restrict__ out_cs,
                                                 float* __restrict__ out_emb,
                                                 float* __restrict__ out_dwb,
                                                 float* __restrict__ out_loss,
                                                 float* __restrict__ out_perp) {
  const int t = threadIdx.x;
  if (blockIdx.x >= 512) {
    const int l = blockIdx.x - 512;
    if (t < 64) {
      float s = 0.f;
#pragma unroll
      for (int i = 0; i < 8; ++i) {
        int k = t * 8 + i;
        float p = countsT[l * 512 + k] * (1.0f / 1024.0f);  // exact: /2^10
        s = __fadd_rn(s, __fmul_rn(p, logf(__fadd_rn(p, 1e-10f))));
      }
#pragma unroll
      for (int off = 32; off > 0; off >>= 1) s += __shfl_down(s, off, 64);
      if (t == 0) out_perp[l] = expf(-s) * (1.0f / 512.0f);
    }
    if (blockIdx.x == 512 && t == 64)
      out_loss[0] = (float)(lossAcc[0] / 4194304.0);  // mean over B*D*L
    return;
  }
  const int k = blockIdx.x;
  __shared__ float dwS[64][65];
  __shared__ float csS[64];
  __shared__ float nS;
  const float* sp = dwT + (size_t)k * 4096;
#pragma unroll
  for (int i = 0; i < 4; ++i) {
    int f4 = t + i * 256;
    float4 v = *(const float4*)&sp[f4 * 4];
    int l = f4 >> 4, d0 = (f4 & 15) * 4;
    dwS[l][d0] = v.x; dwS[l][d0 + 1] = v.y; dwS[l][d0 + 2] = v.z; dwS[l][d0 + 3] = v.w;
  }
  const float* cp = cluster + k * 64;
  if (t == 0) {
    float n = 0.f;
#pragma unroll
    for (int l = 0; l < 64; ++l) n = __fadd_rn(n, cp[l]);
    nS = __fadd_rn(n, 1e-06f);
  }
  __syncthreads();
  if (t < 64) {
    const float n = nS;
    const float denom = __fadd_rn(n, 0.000512f);  // n + K*EPS
    float t1 = __fadd_rn(cp[t], 1e-06f);
    float r = __fdiv_rn(t1, denom);
    float r2 = __fmul_rn(r, n);
    float cs = __fadd_rn(__fmul_rn(0.99f, r2), __fmul_rn(0.01f, countsT[t * 512 + k]));
    csS[t] = cs;
    out_cs[k * 64 + t] = cs;
  }
  __syncthreads();
  const int l = t & 63;
  const int dlane = t >> 6;
#pragma unroll
  for (int r = 0; r < 16; ++r) {
    int d = r * 4 + dlane;
    int g = d * 32768 + k * 64 + l;
    float batch = dwS[l][d];
    float buf = 0.99f * dw[g] + 0.01f * (batch / csS[l]);
    out_dwb[g] = buf;
    out_emb[g] = 0.99f * emb[g] + 0.01f * buf;
  }
}

extern "C" void kernel_launch(void* const* d_in, const int* in_sizes, int n_in,
                              void* d_out, int out_size, void* d_ws, size_t ws_size,
                              hipStream_t stream) {
  (void)in_sizes; (void)n_in; (void)out_size; (void)ws_size;
  const float* x    = (const float*)d_in[0];
  const float* emb  = (const float*)d_in[1];
  const float* dw   = (const float*)d_in[2];
  const float* clus = (const float*)d_in[3];

  float* out = (float*)d_out;
  float* out_q    = out;                 // 4194304
  float* out_enc  = out + 4194304;       // 33554432
  float* out_loss = out + 37748736;      // 1
  float* out_perp = out + 37748737;      // 64
  float* out_emb  = out + 37748801;      // 2097152
  float* out_dwb  = out + 39845953;      // 2097152
  float* out_cs   = out + 41943105;      // 32768

  float* wsf = (float*)d_ws;
  float*  dwT     = wsf;                      // 2,097,152 floats (8 MB)
  float*  countsT = wsf + 2097152;            // 32768 (zeroed in K1)
  float*  eT      = wsf + 2129920;            // 2,097,152 (8 MB)
  float*  e2T     = wsf + 4227072;            // 32768
  int*    idxb    = (int*)(wsf + 4259840);    // 65536
  int*    idxT    = (int*)(wsf + 4325376);    // 65536
  double* lossA   = (double*)(wsf + 4390912); // 8 B (zeroed in K1)
  float*  xT      = wsf + 4456448;            // 4,194,304 floats (16 MB)

  ktransAll<<<1536, 256, 0, stream>>>(emb, x, eT, e2T, xT, countsT, lossA);
  kargmin<<<dim3(64, 8), 256, 0, stream>>>(xT, eT, e2T, idxb, idxT, countsT);
  kdwgather<<<1280, 256, 0, stream>>>(x, xT, eT, idxb, idxT, dwT, out_q, out_enc, lossA);
  kemafinal<<<576, 256, 0, stream>>>(clus, countsT, dw, emb, dwT, lossA,
                                     out_cs, out_emb, out_dwb, out_loss, out_perp);
}

// Round 17
// 133.807 us; speedup vs baseline: 2.2930x; 1.0692x over previous
//
#include <hip/hip_runtime.h>

// Problem constants: B=1024, D=64, K=512, L=64 (h*w=8*8)
// x:        (B,D,L)   b*4096 + d*64 + l
// emb/dw:   (D,K,L)   d*32768 + k*64 + l
// eT:       (L,K,D)   (l*512 + k)*64 + d
// e2T:      (L,K)     l*512 + k
// countsT:  (L,K)     l*512 + k   (exact integer counts as float, via f32 atomics)
// dwT:      (K,L,D)   (k*64 + l)*64 + d
// xT:       (L,B,D)   (l*1024 + b)*64 + d  -- in WS, written by K1.
// idxb:     (B,L), idxT: (L,B)
// FINAL (r17 = verified r11, 132.5us): K2 is LDS-pipe-bound (~41us floor) +
// compiler's vmcnt(0)-drain-before-barrier exposure; prefetch variants (r16)
// and scalar-operand variants (r13-15) both regressed. K2 grid is (l, b-tile)
// so blocks sharing an eT slab co-locate on one XCD (id%8 = l%8).

typedef float f32x4 __attribute__((ext_vector_type(4)));

// ---------------- K1: fused emb transpose + e2 | x transpose | zero counts/loss ----------------
__global__ __launch_bounds__(256) void ktransAll(const float* __restrict__ emb,
                                                 const float* __restrict__ x,
                                                 float* __restrict__ eT,
                                                 float* __restrict__ e2T,
                                                 float* __restrict__ xT,
                                                 float* __restrict__ countsT,
                                                 double* __restrict__ lossAcc) {
  const int t = threadIdx.x;
  __shared__ float s[64][65];
  if (blockIdx.x < 512) {
    const int k = blockIdx.x;
#pragma unroll
    for (int i = 0; i < 16; ++i) {
      int e = t + i * 256;
      int d = e >> 6, l = e & 63;
      s[d][l] = emb[d * 32768 + k * 64 + l];
    }
    __syncthreads();
    if (t < 64) {
      float s2 = 0.f;
#pragma unroll
      for (int d = 0; d < 64; ++d) {
        float v = s[d][t];
        s2 = __fadd_rn(s2, __fmul_rn(v, v));  // round(v*v), sequential-d sum like ref
      }
      e2T[t * 512 + k] = s2;
      countsT[k * 64 + t] = 0.f;   // all 32768 entries zeroed across 512 blocks
    }
    if (k == 0 && t == 0) lossAcc[0] = 0.0;
#pragma unroll
    for (int i = 0; i < 4; ++i) {
      int j = t + i * 256;
      int l = j >> 4, d0 = (j & 15) * 4;
      float4 w;
      w.x = s[d0][l]; w.y = s[d0 + 1][l]; w.z = s[d0 + 2][l]; w.w = s[d0 + 3][l];
      *(float4*)&eT[(l * 512 + k) * 64 + d0] = w;
    }
  } else {
    const int b = blockIdx.x - 512;
    const float* xp = x + b * 4096;
#pragma unroll
    for (int i = 0; i < 4; ++i) {
      int f4 = t + i * 256;
      float4 v = *(const float4*)&xp[f4 * 4];
      int d = f4 >> 4, l0 = (f4 & 15) * 4;
      s[d][l0] = v.x; s[d][l0 + 1] = v.y; s[d][l0 + 2] = v.z; s[d][l0 + 3] = v.w;
    }
    __syncthreads();
#pragma unroll
    for (int i = 0; i < 4; ++i) {
      int j = t + i * 256;
      int l = j >> 4, d0 = (j & 15) * 4;
      float4 w;
      w.x = s[d0][l]; w.y = s[d0 + 1][l]; w.z = s[d0 + 2][l]; w.w = s[d0 + 3][l];
      *(float4*)&xT[((size_t)l * 1024 + b) * 64 + d0] = w;
    }
  }
}

// ---------------- K2: argmin distance GEMM (coalesced xT reads, XCD-local eT) ----------------
// grid (64, 8): x = l, y = b-tile of 128. 256 threads: bg = t&15, kg = t>>4.
// 4 chunks of 128 k-cols; LDS ~70 KB -> 2 blocks/CU.
__global__ __launch_bounds__(256, 2) void kargmin(const float* __restrict__ xT,
                                                  const float* __restrict__ eT,
                                                  const float* __restrict__ e2T,
                                                  int* __restrict__ idxout,
                                                  int* __restrict__ idxTout,
                                                  float* __restrict__ countsT) {
  const int l = blockIdx.x;                // XCD = l % 8 -> eT slab L2-local
  const int b0 = blockIdx.y * 128;
  const int t = threadIdx.x;
  __shared__ float xs[128][68];
  __shared__ float es[128][68];
  __shared__ float e2s[128];
  const float* xsrc = xT + ((size_t)l * 1024 + b0) * 64;
#pragma unroll
  for (int i = 0; i < 8; ++i) {
    int f4 = t + i * 256;             // 2048 float4 = 128x64, fully coalesced
    int r = f4 >> 4;
    int c = (f4 & 15) * 4;
    *(float4*)&xs[r][c] = *(const float4*)&xsrc[f4 * 4];
  }
  const int bg = t & 15;
  const int kg = t >> 4;
  float bestv[8];
  int bestk[8];
#pragma unroll
  for (int i = 0; i < 8; ++i) { bestv[i] = 3.4e38f; bestk[i] = 0; }

  for (int chunk = 0; chunk < 4; ++chunk) {
    __syncthreads();  // xs ready (iter 0) / prev compute done before es overwrite
    const float* src = eT + (l * 512 + chunk * 128) * 64;
#pragma unroll
    for (int i = 0; i < 8; ++i) {
      int f4 = t + i * 256;            // 2048 float4 = 128x64
      int r = f4 >> 4;
      int c = (f4 & 15) * 4;
      *(float4*)&es[r][c] = *(const float4*)&src[f4 * 4];
    }
    if (t < 128) e2s[t] = e2T[l * 512 + chunk * 128 + t];
    __syncthreads();

    float acc[8][8];
#pragma unroll
    for (int i = 0; i < 8; ++i)
#pragma unroll
      for (int j = 0; j < 8; ++j) acc[i][j] = 0.f;

    for (int d4 = 0; d4 < 16; ++d4) {
      float4 xv[8], ev[8];
#pragma unroll
      for (int i = 0; i < 8; ++i) xv[i] = *(const float4*)&xs[bg + i * 16][d4 * 4];
#pragma unroll
      for (int j = 0; j < 8; ++j) ev[j] = *(const float4*)&es[kg + j * 16][d4 * 4];
#pragma unroll
      for (int i = 0; i < 8; ++i)
#pragma unroll
        for (int j = 0; j < 8; ++j) {
          acc[i][j] = fmaf(xv[i].x, ev[j].x, acc[i][j]);
          acc[i][j] = fmaf(xv[i].y, ev[j].y, acc[i][j]);
          acc[i][j] = fmaf(xv[i].z, ev[j].z, acc[i][j]);
          acc[i][j] = fmaf(xv[i].w, ev[j].w, acc[i][j]);
        }
    }
#pragma unroll
    for (int j = 0; j < 8; ++j) {
      int kk = kg + j * 16;
      int kglob = chunk * 128 + kk;
      float e2v = e2s[kk];
#pragma unroll
      for (int i = 0; i < 8; ++i) {
        float d2 = fmaf(-2.0f, acc[i][j], e2v);  // e2 - 2*xe, single rounding
        if (d2 < bestv[i] || (d2 == bestv[i] && kglob < bestk[i])) {
          bestv[i] = d2; bestk[i] = kglob;
        }
      }
    }
  }
  __syncthreads();
  // cross-kg reduction; reuse es (vals) and xs (k as float, exact for k<512)
  float* rv = &es[0][0];
  float* rkf = &xs[0][0];
#pragma unroll
  for (int i = 0; i < 8; ++i) {
    int bl = bg + i * 16;
    rv[bl * 16 + kg] = bestv[i];
    rkf[bl * 16 + kg] = (float)bestk[i];
  }
  __syncthreads();
  if (t < 128) {
    float bv = rv[t * 16];
    int bk = (int)rkf[t * 16];
#pragma unroll
    for (int g = 1; g < 16; ++g) {
      float v = rv[t * 16 + g];
      int kk = (int)rkf[t * 16 + g];
      if (v < bv || (v == bv && kk < bk)) { bv = v; bk = kk; }
    }
    idxout[(b0 + t) * 64 + l] = bk;
    idxTout[l * 1024 + b0 + t] = bk;
    unsafeAtomicAdd(&countsT[l * 512 + bk], 1.0f);  // integer counts: exact any order
  }
}

// ---------------- K3: role-split — dw-accumulate (256 blocks) + gather (1024 blocks) ----------------
__global__ __launch_bounds__(256) void kdwgather(const float* __restrict__ x,
                                                 const float* __restrict__ xT,
                                                 const float* __restrict__ eT,
                                                 const int* __restrict__ idxb,
                                                 const int* __restrict__ idxT,
                                                 float* __restrict__ dwT,
                                                 float* __restrict__ out_q,
                                                 float* __restrict__ out_enc,
                                                 double* __restrict__ lossAcc) {
  const int t = threadIdx.x;
  __shared__ float SM[8192];   // 32 KB, reused per role
  if (blockIdx.x < 256) {
    // ---- dw-accumulate: block = (l = blk&63, kq = (blk>>6)*128); XCD = l%8 ----
    const int l = blockIdx.x & 63;
    const int kq = (blockIdx.x >> 6) * 128;
    float* acc = SM;  // 128 k x 64 d
#pragma unroll
    for (int i = 0; i < 32; ++i) acc[t + i * 256] = 0.f;
    const int w = t >> 6, lane = t & 63;
    __syncthreads();
    const int* idxl = idxT + l * 1024;
    const float* xTl = xT + (size_t)l * 65536;
    for (int c = 0; c < 4; ++c) {
      const int base = w * 256 + c * 64;
      const int myidx = idxl[base + lane];
      // 8-wide batching + coalesced xT loads (256B per wave-load)
      for (int jj = 0; jj < 64; jj += 8) {
        int ks[8]; float vs[8];
#pragma unroll
        for (int u = 0; u < 8; ++u) ks[u] = __shfl(myidx, jj + u, 64) - kq;  // wave-uniform
#pragma unroll
        for (int u = 0; u < 8; ++u)
          if ((unsigned)ks[u] < 128u)
            vs[u] = xTl[(size_t)(base + jj + u) * 64 + lane];  // coalesced
#pragma unroll
        for (int u = 0; u < 8; ++u)
          if ((unsigned)ks[u] < 128u)
            atomicAdd(&acc[(ks[u] << 6) + lane], vs[u]);  // ds_add_f32, bank-clean
      }
    }
    __syncthreads();
#pragma unroll
    for (int i = 0; i < 32; ++i) {
      int e = t + i * 256;
      int k = e >> 6, d = e & 63;
      dwT[((size_t)(kq + k) * 64 + l) * 64 + d] = acc[e];
    }
  } else {
    // ---- gather/quantized/one-hot/loss: b = blk - 256 ----
    const int b = blockIdx.x - 256;
    float (*qb)[68] = (float (*)[68])SM;    // 64x68 = 4352
    int* lidx = (int*)(SM + 4352);          // 64
    double* wsumS = (double*)(SM + 4432);   // 8-aligned (float idx 4432 = byte 17728)
    if (t < 64) lidx[t] = idxb[b * 64 + t];
    __syncthreads();
    const int l = t >> 2, qd = (t & 3) * 16;
    const int kse = lidx[l];
    const float* ep = eT + (l * 512 + kse) * 64 + qd;
#pragma unroll
    for (int j = 0; j < 4; ++j) {
      float4 v = *(const float4*)&ep[j * 4];
      qb[qd + j * 4 + 0][l] = v.x;
      qb[qd + j * 4 + 1][l] = v.y;
      qb[qd + j * 4 + 2][l] = v.z;
      qb[qd + j * 4 + 3][l] = v.w;
    }
    __syncthreads();
    float ls = 0.f;
    const float* xp = x + b * 4096;
    float* op = out_q + b * 4096;
#pragma unroll
    for (int i = 0; i < 4; ++i) {
      int f4 = t + i * 256;
      float4 xv = *(const float4*)&xp[f4 * 4];
      int d = f4 >> 4, l0 = (f4 & 15) * 4;
      float4 qv = *(const float4*)&qb[d][l0];
      f32x4 ov;
      float dx = qv.x - xv.x, dy = qv.y - xv.y, dz = qv.z - xv.z, dw_ = qv.w - xv.w;
      ov.x = xv.x + dx; ov.y = xv.y + dy; ov.z = xv.z + dz; ov.w = xv.w + dw_;
      __builtin_nontemporal_store(ov, (f32x4*)&op[f4 * 4]);  // x + (q - x), streamed
      ls = fmaf(dx, dx, ls); ls = fmaf(dy, dy, ls);
      ls = fmaf(dz, dz, ls); ls = fmaf(dw_, dw_, ls);
    }
    // dense one-hot row (128 KB per block, nontemporal streaming)
    float* encp = out_enc + (size_t)b * 32768;
#pragma unroll
    for (int i = 0; i < 32; ++i) {
      int f4 = t + i * 256;
      int e = f4 * 4;
      int k = e >> 6, l0 = e & 63;
      f32x4 v;
      v.x = (lidx[l0 + 0] == k) ? 1.f : 0.f;
      v.y = (lidx[l0 + 1] == k) ? 1.f : 0.f;
      v.z = (lidx[l0 + 2] == k) ? 1.f : 0.f;
      v.w = (lidx[l0 + 3] == k) ? 1.f : 0.f;
      __builtin_nontemporal_store(v, (f32x4*)&encp[e]);
    }
#pragma unroll
    for (int off = 32; off > 0; off >>= 1) ls += __shfl_down(ls, off, 64);
    if ((t & 63) == 0) wsumS[t >> 6] = (double)ls;
    __syncthreads();
    if (t == 0) unsafeAtomicAdd(lossAcc, wsumS[0] + wsumS[1] + wsumS[2] + wsumS[3]);
  }
}

// ---------------- K4: cs + EMA (k=blk) | perplexity (blk>=512) + loss ----------------
__global__ __launch_bounds__(256) void kemafinal(const float* __restrict__ cluster,
                                                 const float* __restrict__ countsT,
                                                 const float* __restrict__ dw,
                                                 const float* __restrict__ emb,
                                                 const float* __restrict__ dwT,
                                                 const double* __restrict__ lossAcc,
                                                 float* __restrict__ out_cs,
                                                 float* __restrict__ out_emb,
                                                 float* __restrict__ out_dwb,
                                                 float* __restrict__ out_loss,
                                                 float* __restrict__ out_perp) {
  const int t = threadIdx.x;
  if (blockIdx.x >= 512) {
    const int l = blockIdx.x - 512;
    if (t < 64) {
      float s = 0.f;
#pragma unroll
      for (int i = 0; i < 8; ++i) {
        int k = t * 8 + i;
        float p = countsT[l * 512 + k] * (1.0f / 1024.0f);  // exact: /2^10
        s = __fadd_rn(s, __fmul_rn(p, logf(__fadd_rn(p, 1e-10f))));
      }
#pragma unroll
      for (int off = 32; off > 0; off >>= 1) s += __shfl_down(s, off, 64);
      if (t == 0) out_perp[l] = expf(-s) * (1.0f / 512.0f);
    }
    if (blockIdx.x == 512 && t == 64)
      out_loss[0] = (float)(lossAcc[0] / 4194304.0);  // mean over B*D*L
    return;
  }
  const int k = blockIdx.x;
  __shared__ float dwS[64][65];
  __shared__ float csS[64];
  __shared__ float nS;
  const float* sp = dwT + (size_t)k * 4096;
#pragma unroll
  for (int i = 0; i < 4; ++i) {
    int f4 = t + i * 256;
    float4 v = *(const float4*)&sp[f4 * 4];
    int l = f4 >> 4, d0 = (f4 & 15) * 4;
    dwS[l][d0] = v.x; dwS[l][d0 + 1] = v.y; dwS[l][d0 + 2] = v.z; dwS[l][d0 + 3] = v.w;
  }
  const float* cp = cluster + k * 64;
  if (t == 0) {
    float n = 0.f;
#pragma unroll
    for (int l = 0; l < 64; ++l) n = __fadd_rn(n, cp[l]);
    nS = __fadd_rn(n, 1e-06f);
  }
  __syncthreads();
  if (t < 64) {
    const float n = nS;
    const float denom = __fadd_rn(n, 0.000512f);  // n + K*EPS
    float t1 = __fadd_rn(cp[t], 1e-06f);
    float r = __fdiv_rn(t1, denom);
    float r2 = __fmul_rn(r, n);
    float cs = __fadd_rn(__fmul_rn(0.99f, r2), __fmul_rn(0.01f, countsT[t * 512 + k]));
    csS[t] = cs;
    out_cs[k * 64 + t] = cs;
  }
  __syncthreads();
  const int l = t & 63;
  const int dlane = t >> 6;
#pragma unroll
  for (int r = 0; r < 16; ++r) {
    int d = r * 4 + dlane;
    int g = d * 32768 + k * 64 + l;
    float batch = dwS[l][d];
    float buf = 0.99f * dw[g] + 0.01f * (batch / csS[l]);
    out_dwb[g] = buf;
    out_emb[g] = 0.99f * emb[g] + 0.01f * buf;
  }
}

extern "C" void kernel_launch(void* const* d_in, const int* in_sizes, int n_in,
                              void* d_out, int out_size, void* d_ws, size_t ws_size,
                              hipStream_t stream) {
  (void)in_sizes; (void)n_in; (void)out_size; (void)ws_size;
  const float* x    = (const float*)d_in[0];
  const float* emb  = (const float*)d_in[1];
  const float* dw   = (const float*)d_in[2];
  const float* clus = (const float*)d_in[3];

  float* out = (float*)d_out;
  float* out_q    = out;                 // 4194304
  float* out_enc  = out + 4194304;       // 33554432
  float* out_loss = out + 37748736;      // 1
  float* out_perp = out + 37748737;      // 64
  float* out_emb  = out + 37748801;      // 2097152
  float* out_dwb  = out + 39845953;      // 2097152
  float* out_cs   = out + 41943105;      // 32768

  float* wsf = (float*)d_ws;
  float*  dwT     = wsf;                      // 2,097,152 floats (8 MB)
  float*  countsT = wsf + 2097152;            // 32768 (zeroed in K1)
  float*  eT      = wsf + 2129920;            // 2,097,152 (8 MB)
  float*  e2T     = wsf + 4227072;            // 32768
  int*    idxb    = (int*)(wsf + 4259840);    // 65536
  int*    idxT    = (int*)(wsf + 4325376);    // 65536
  double* lossA   = (double*)(wsf + 4390912); // 8 B (zeroed in K1)
  float*  xT      = wsf + 4456448;            // 4,194,304 floats (16 MB), 256-aligned

  ktransAll<<<1536, 256, 0, stream>>>(emb, x, eT, e2T, xT, countsT, lossA);
  kargmin<<<dim3(64, 8), 256, 0, stream>>>(xT, eT, e2T, idxb, idxT, countsT);
  kdwgather<<<1280, 256, 0, stream>>>(x, xT, eT, idxb, idxT, dwT, out_q, out_enc, lossA);
  kemafinal<<<576, 256, 0, stream>>>(clus, countsT, dw, emb, dwT, lossA,
                                     out_cs, out_emb, out_dwb, out_loss, out_perp);
}